// Round 2
// baseline (362.038 us; speedup 1.0000x reference)
//
#include <hip/hip_runtime.h>
#include <hip/hip_bf16.h>

#define NN 50000
#define NE 800000
#define NG 512
#define IND 128
#define MIDD 12

// ---------------- fold weights: W1eff=[256,12], b1eff, W2eff=[24,12], b2eff ----
__global__ void fold_kernel(const float* __restrict__ W1a, const float* __restrict__ b1a,
                            const float* __restrict__ W1b, const float* __restrict__ b1b,
                            const float* __restrict__ W2a, const float* __restrict__ b2a,
                            const float* __restrict__ W2b, const float* __restrict__ b2b,
                            float* __restrict__ W1eff, float* __restrict__ b1eff,
                            float* __restrict__ W2eff, float* __restrict__ b2eff) {
    int t = blockIdx.x * blockDim.x + threadIdx.x;
    if (t < 3072) {
        int r = t / 12, c = t % 12;
        float acc = 0.f;
        for (int k = 0; k < 256; ++k) acc += W1a[r*256 + k] * W1b[k*12 + c];
        W1eff[r*12 + c] = acc;
    } else if (t < 3084) {
        int c = t - 3072;
        float acc = b1b[c];
        for (int k = 0; k < 256; ++k) acc += b1a[k] * W1b[k*12 + c];
        b1eff[c] = acc;
    } else if (t < 3372) {
        int u = t - 3084;
        int r = u / 12, c = u % 12;
        float acc = 0.f;
        for (int k = 0; k < 256; ++k) acc += W2a[r*256 + k] * W2b[k*12 + c];
        W2eff[r*12 + c] = acc;
    } else if (t < 3384) {
        int c = t - 3372;
        float acc = b2b[c];
        for (int k = 0; k < 256; ++k) acc += b2a[k] * W2b[k*12 + c];
        b2eff[c] = acc;
    }
}

// ---------------- p1: h [NN,128] @ W1eff -> p1_top [NN,12], p1_bot [NN,12] -----
__global__ void p1_kernel(const float* __restrict__ h, const float* __restrict__ W1eff,
                          float* __restrict__ p1t, float* __restrict__ p1b) {
    __shared__ float wsm[256 * 12];
    __shared__ float hs[16 * 129];
    int tid = threadIdx.x;
    for (int i = tid; i < 3072; i += 256) wsm[i] = W1eff[i];
    int node0 = blockIdx.x * 16;
    for (int i = tid; i < 16 * 128; i += 256) {
        int nl = i >> 7, k = i & 127;
        int n = node0 + nl;
        hs[nl * 129 + k] = (n < NN) ? h[n * 128 + k] : 0.0f;
    }
    __syncthreads();
    for (int idx = tid; idx < 16 * 24; idx += 256) {
        int nl = idx / 24, c = idx % 24;
        int n = node0 + nl;
        if (n >= NN) continue;
        const float* hrow = &hs[nl * 129];
        float acc = 0.f;
        if (c < 12) {
            #pragma unroll
            for (int k = 0; k < 128; ++k) acc += hrow[k] * wsm[k*12 + c];
            p1t[n*12 + c] = acc;
        } else {
            int cc = c - 12;
            #pragma unroll
            for (int k = 0; k < 128; ++k) acc += hrow[k] * wsm[(128+k)*12 + cc];
            p1b[n*12 + cc] = acc;
        }
    }
}

// ---------------- CSR build: deg histogram -------------------------------------
__global__ void deg_kernel(const int* __restrict__ dst, int* __restrict__ deg) {
    int e = blockIdx.x * blockDim.x + threadIdx.x;
    if (e >= NE) return;
    atomicAdd(&deg[dst[e]], 1);
}

// ---------------- CSR build: exclusive prefix sum (single block) ---------------
__global__ void scan_kernel(const int* __restrict__ deg, int* __restrict__ row_start) {
    __shared__ int part[1024];
    const int CH = 49;  // 1024*49 = 50176 >= NN
    int tid = threadIdx.x;
    int base = tid * CH;
    int s = 0;
    for (int i = 0; i < CH; ++i) {
        int idx = base + i;
        if (idx < NN) s += deg[idx];
    }
    part[tid] = s;
    __syncthreads();
    // Hillis-Steele inclusive scan
    for (int off = 1; off < 1024; off <<= 1) {
        int v = (tid >= off) ? part[tid - off] : 0;
        __syncthreads();
        part[tid] += v;
        __syncthreads();
    }
    int run = (tid > 0) ? part[tid - 1] : 0;  // exclusive prefix of this chunk
    for (int i = 0; i < CH; ++i) {
        int idx = base + i;
        if (idx <= NN) row_start[idx] = run;
        if (idx < NN) run += deg[idx];
    }
}

// ---------------- CSR build: scatter src into buckets --------------------------
__global__ void scatter_kernel(const int* __restrict__ src, const int* __restrict__ dst,
                               const int* __restrict__ row_start, int* __restrict__ cursor,
                               int* __restrict__ sorted_src) {
    int e = blockIdx.x * blockDim.x + threadIdx.x;
    if (e >= NE) return;
    int d = dst[e];
    int pos = row_start[d] + atomicAdd(&cursor[d], 1);
    sorted_src[pos] = src[e];
}

// ---------------- gather: acc[n,c] = sum over in-edges of p[src,c] -------------
__global__ void gather_kernel(const int* __restrict__ row_start, const int* __restrict__ sorted_src,
                              const float* __restrict__ p, float* __restrict__ acc) {
    int t = blockIdx.x * blockDim.x + threadIdx.x;
    if (t >= NN * 12) return;
    int n = t / 12, c = t - n * 12;
    int r0 = row_start[n], r1 = row_start[n + 1];
    float s = 0.f;
    for (int i = r0; i < r1; ++i) {
        int sn = sorted_src[i];
        s += p[sn * 12 + c];
    }
    acc[t] = s;
}

// ---------------- finalize layer1 + compute p2_top/p2_bot ----------------------
__global__ void finalize1_kernel(const float* __restrict__ p1t, const float* __restrict__ acc1,
                                 const int* __restrict__ deg, const float* __restrict__ b1eff,
                                 const float* __restrict__ W2eff,
                                 float* __restrict__ p2t, float* __restrict__ p2b) {
    __shared__ float w2[288];
    __shared__ float b1[12];
    int tid = threadIdx.x;
    for (int i = tid; i < 288; i += 256) w2[i] = W2eff[i];
    if (tid < 12) b1[tid] = b1eff[tid];
    __syncthreads();
    int n = blockIdx.x * blockDim.x + tid;
    if (n >= NN) return;
    int dg = deg[n];
    float inv = dg > 0 ? 1.f / (float)dg : 0.f;
    float h1[12];
    #pragma unroll
    for (int j = 0; j < 12; ++j) {
        float v = p1t[n*12 + j] + acc1[n*12 + j] * inv + b1[j];
        h1[j] = v > 0.f ? v : 0.f;
    }
    #pragma unroll
    for (int co = 0; co < 12; ++co) {
        float a = 0.f, b = 0.f;
        #pragma unroll
        for (int k = 0; k < 12; ++k) {
            a += h1[k] * w2[k*12 + co];
            b += h1[k] * w2[(12+k)*12 + co];
        }
        p2t[n*12 + co] = a;
        p2b[n*12 + co] = b;
    }
}

// ---------------- finalize layer2 + graph pooling ------------------------------
__global__ void finalize2_kernel(const float* __restrict__ p2t, const float* __restrict__ acc2,
                                 const int* __restrict__ deg, const float* __restrict__ b2eff,
                                 const int* __restrict__ graph_id,
                                 float* __restrict__ accg, float* __restrict__ cntg) {
    __shared__ float b2[12];
    if (threadIdx.x < 12) b2[threadIdx.x] = b2eff[threadIdx.x];
    __syncthreads();
    int n = blockIdx.x * blockDim.x + threadIdx.x;
    if (n >= NN) return;
    int dg = deg[n];
    float inv = dg > 0 ? 1.f / (float)dg : 0.f;
    int g = graph_id[n];
    #pragma unroll
    for (int j = 0; j < 12; ++j) {
        float v = p2t[n*12 + j] + acc2[n*12 + j] * inv + b2[j];
        v = v > 0.f ? v : 0.f;
        atomicAdd(&accg[g*12 + j], v);
    }
    atomicAdd(&cntg[g], 1.0f);
}

// ---------------- output: hg @ Wc + bc -----------------------------------------
__global__ void out_kernel(const float* __restrict__ accg, const float* __restrict__ cntg,
                           const float* __restrict__ Wc, const float* __restrict__ bc,
                           float* __restrict__ out) {
    int t = blockIdx.x * blockDim.x + threadIdx.x;
    if (t >= NG * 10) return;
    int g = t / 10, cls = t - g * 10;
    float c = cntg[g];
    float inv = c > 0.f ? 1.f / c : 0.f;
    float acc = bc[cls];
    #pragma unroll
    for (int j = 0; j < 12; ++j) acc += accg[g*12 + j] * inv * Wc[j*10 + cls];
    out[t] = acc;
}

extern "C" void kernel_launch(void* const* d_in, const int* in_sizes, int n_in,
                              void* d_out, int out_size, void* d_ws, size_t ws_size,
                              hipStream_t stream) {
    const float* h   = (const float*)d_in[0];
    const int* src   = (const int*)d_in[1];
    const int* dst   = (const int*)d_in[2];
    const int* gid   = (const int*)d_in[3];
    const float* W1a = (const float*)d_in[4];
    const float* b1a = (const float*)d_in[5];
    const float* W1b = (const float*)d_in[6];
    const float* b1b = (const float*)d_in[7];
    const float* W2a = (const float*)d_in[8];
    const float* b2a = (const float*)d_in[9];
    const float* W2b = (const float*)d_in[10];
    const float* b2b = (const float*)d_in[11];
    const float* Wc  = (const float*)d_in[12];
    const float* bc  = (const float*)d_in[13];
    float* out = (float*)d_out;

    float* ws = (float*)d_ws;
    float* W1eff = ws;                    // 3072
    float* b1eff = ws + 3072;             // 12
    float* W2eff = ws + 3084;             // 288
    float* b2eff = ws + 3372;             // 12 -> 3384
    float* p1t   = ws + 3384;             // 600000
    float* p1b   = ws + 603384;           // 600000
    float* p2t   = ws + 1203384;          // 600000
    float* p2b   = ws + 1803384;          // 600000
    float* acc1  = ws + 2403384;          // 600000 (written directly, no zero needed)
    float* acc2  = ws + 3003384;          // 600000
    // ---- zeroed region starts here (accg, cntg, deg, cursor contiguous) ----
    float* accg  = ws + 3603384;          // 6144
    float* cntg  = ws + 3609528;          // 512
    int*   deg        = (int*)(ws + 3610040);   // 50000
    int*   cursor     = (int*)(ws + 3660040);   // 50000
    // ---- end zeroed region ----
    int*   row_start  = (int*)(ws + 3710040);   // 50001
    int*   sorted_src = (int*)(ws + 3760041);   // 800000  -> total ~18.2 MB

    hipMemsetAsync(accg, 0, (size_t)(6144 + 512 + 50000 + 50000) * sizeof(float), stream);

    fold_kernel<<<14, 256, 0, stream>>>(W1a, b1a, W1b, b1b, W2a, b2a, W2b, b2b,
                                        W1eff, b1eff, W2eff, b2eff);

    p1_kernel<<<(NN + 15) / 16, 256, 0, stream>>>(h, W1eff, p1t, p1b);

    deg_kernel<<<(NE + 255) / 256, 256, 0, stream>>>(dst, deg);
    scan_kernel<<<1, 1024, 0, stream>>>(deg, row_start);
    scatter_kernel<<<(NE + 255) / 256, 256, 0, stream>>>(src, dst, row_start, cursor, sorted_src);

    gather_kernel<<<(NN * 12 + 255) / 256, 256, 0, stream>>>(row_start, sorted_src, p1b, acc1);
    finalize1_kernel<<<(NN + 255) / 256, 256, 0, stream>>>(p1t, acc1, deg, b1eff, W2eff, p2t, p2b);

    gather_kernel<<<(NN * 12 + 255) / 256, 256, 0, stream>>>(row_start, sorted_src, p2b, acc2);
    finalize2_kernel<<<(NN + 255) / 256, 256, 0, stream>>>(p2t, acc2, deg, b2eff, gid, accg, cntg);

    out_kernel<<<(NG * 10 + 255) / 256, 256, 0, stream>>>(accg, cntg, Wc, bc, out);
}

// Round 3
// 264.899 us; speedup vs baseline: 1.3667x; 1.3667x over previous
//
#include <hip/hip_runtime.h>
#include <hip/hip_bf16.h>

#define NN 50000
#define NE 800000
#define NG 512
#define IND 128
#define MIDD 12
#define SCAN_BLOCKS 196   // 196*256 = 50176 >= NN+1

// ---------------- fold weights: W1eff=[256,12], b1eff, W2eff=[24,12], b2eff ----
__global__ void fold_kernel(const float* __restrict__ W1a, const float* __restrict__ b1a,
                            const float* __restrict__ W1b, const float* __restrict__ b1b,
                            const float* __restrict__ W2a, const float* __restrict__ b2a,
                            const float* __restrict__ W2b, const float* __restrict__ b2b,
                            float* __restrict__ W1eff, float* __restrict__ b1eff,
                            float* __restrict__ W2eff, float* __restrict__ b2eff) {
    int t = blockIdx.x * blockDim.x + threadIdx.x;
    if (t < 3072) {
        int r = t / 12, c = t % 12;
        float acc = 0.f;
        for (int k = 0; k < 256; ++k) acc += W1a[r*256 + k] * W1b[k*12 + c];
        W1eff[r*12 + c] = acc;
    } else if (t < 3084) {
        int c = t - 3072;
        float acc = b1b[c];
        for (int k = 0; k < 256; ++k) acc += b1a[k] * W1b[k*12 + c];
        b1eff[c] = acc;
    } else if (t < 3372) {
        int u = t - 3084;
        int r = u / 12, c = u % 12;
        float acc = 0.f;
        for (int k = 0; k < 256; ++k) acc += W2a[r*256 + k] * W2b[k*12 + c];
        W2eff[r*12 + c] = acc;
    } else if (t < 3384) {
        int c = t - 3372;
        float acc = b2b[c];
        for (int k = 0; k < 256; ++k) acc += b2a[k] * W2b[k*12 + c];
        b2eff[c] = acc;
    }
}

// ---------------- p1: h [NN,128] @ W1eff -> p1_top [NN,12], p1_bot [NN,12] -----
__global__ void p1_kernel(const float* __restrict__ h, const float* __restrict__ W1eff,
                          float* __restrict__ p1t, float* __restrict__ p1b) {
    __shared__ float wsm[256 * 12];
    __shared__ float hs[16 * 129];
    int tid = threadIdx.x;
    for (int i = tid; i < 3072; i += 256) wsm[i] = W1eff[i];
    int node0 = blockIdx.x * 16;
    for (int i = tid; i < 16 * 128; i += 256) {
        int nl = i >> 7, k = i & 127;
        int n = node0 + nl;
        hs[nl * 129 + k] = (n < NN) ? h[n * 128 + k] : 0.0f;
    }
    __syncthreads();
    for (int idx = tid; idx < 16 * 24; idx += 256) {
        int nl = idx / 24, c = idx % 24;
        int n = node0 + nl;
        if (n >= NN) continue;
        const float* hrow = &hs[nl * 129];
        float acc = 0.f;
        if (c < 12) {
            #pragma unroll
            for (int k = 0; k < 128; ++k) acc += hrow[k] * wsm[k*12 + c];
            p1t[n*12 + c] = acc;
        } else {
            int cc = c - 12;
            #pragma unroll
            for (int k = 0; k < 128; ++k) acc += hrow[k] * wsm[(128+k)*12 + cc];
            p1b[n*12 + cc] = acc;
        }
    }
}

// ---------------- CSR build: deg histogram -------------------------------------
__global__ void deg_kernel(const int* __restrict__ dst, int* __restrict__ deg) {
    int e = blockIdx.x * blockDim.x + threadIdx.x;
    if (e >= NE) return;
    atomicAdd(&deg[dst[e]], 1);
}

// ---------------- parallel scan stage 1: per-block sums ------------------------
__global__ void bsum_kernel(const int* __restrict__ deg, int* __restrict__ bsums) {
    __shared__ int sh[256];
    int tid = threadIdx.x;
    int i = blockIdx.x * 256 + tid;
    sh[tid] = (i < NN) ? deg[i] : 0;
    __syncthreads();
    for (int off = 128; off > 0; off >>= 1) {
        if (tid < off) sh[tid] += sh[tid + off];
        __syncthreads();
    }
    if (tid == 0) bsums[blockIdx.x] = sh[0];
}

// ---------------- parallel scan stage 2: scan block sums (1 block) -------------
__global__ void bscan_kernel(const int* __restrict__ bsums, int* __restrict__ boffs) {
    __shared__ int sh[256];
    int tid = threadIdx.x;
    int v = (tid < SCAN_BLOCKS) ? bsums[tid] : 0;
    sh[tid] = v;
    __syncthreads();
    for (int off = 1; off < 256; off <<= 1) {
        int t = (tid >= off) ? sh[tid - off] : 0;
        __syncthreads();
        sh[tid] += t;
        __syncthreads();
    }
    if (tid < SCAN_BLOCKS) boffs[tid] = sh[tid] - v;  // exclusive
}

// ---------------- parallel scan stage 3: per-block exclusive scan + write ------
__global__ void rowscan_kernel(const int* __restrict__ deg, const int* __restrict__ boffs,
                               int* __restrict__ row_start) {
    __shared__ int sh[256];
    int tid = threadIdx.x;
    int i = blockIdx.x * 256 + tid;
    int v = (i < NN) ? deg[i] : 0;
    sh[tid] = v;
    __syncthreads();
    for (int off = 1; off < 256; off <<= 1) {
        int t = (tid >= off) ? sh[tid - off] : 0;
        __syncthreads();
        sh[tid] += t;
        __syncthreads();
    }
    if (i <= NN) row_start[i] = boffs[blockIdx.x] + sh[tid] - v;
}

// ---------------- CSR build: scatter src into buckets --------------------------
__global__ void scatter_kernel(const int* __restrict__ src, const int* __restrict__ dst,
                               const int* __restrict__ row_start, int* __restrict__ cursor,
                               int* __restrict__ sorted_src) {
    int e = blockIdx.x * blockDim.x + threadIdx.x;
    if (e >= NE) return;
    int d = dst[e];
    int pos = row_start[d] + atomicAdd(&cursor[d], 1);
    sorted_src[pos] = src[e];
}

// ---------------- gather: acc[n,c] = sum over in-edges of p[src,c] -------------
__global__ void gather_kernel(const int* __restrict__ row_start, const int* __restrict__ sorted_src,
                              const float* __restrict__ p, float* __restrict__ acc) {
    int t = blockIdx.x * blockDim.x + threadIdx.x;
    if (t >= NN * 12) return;
    int n = t / 12, c = t - n * 12;
    int r0 = row_start[n], r1 = row_start[n + 1];
    float s = 0.f;
    if (r0 < r1) {
        int sn = sorted_src[r0];                 // software-pipelined: next index
        for (int i = r0 + 1; i < r1; ++i) {      // prefetched while p-load in flight
            int sn_next = sorted_src[i];
            s += p[sn * 12 + c];
            sn = sn_next;
        }
        s += p[sn * 12 + c];
    }
    acc[t] = s;
}

// ---------------- finalize layer1 + compute p2_top/p2_bot ----------------------
__global__ void finalize1_kernel(const float* __restrict__ p1t, const float* __restrict__ acc1,
                                 const int* __restrict__ deg, const float* __restrict__ b1eff,
                                 const float* __restrict__ W2eff,
                                 float* __restrict__ p2t, float* __restrict__ p2b) {
    __shared__ float w2[288];
    __shared__ float b1[12];
    int tid = threadIdx.x;
    for (int i = tid; i < 288; i += 256) w2[i] = W2eff[i];
    if (tid < 12) b1[tid] = b1eff[tid];
    __syncthreads();
    int n = blockIdx.x * blockDim.x + tid;
    if (n >= NN) return;
    int dg = deg[n];
    float inv = dg > 0 ? 1.f / (float)dg : 0.f;
    float h1[12];
    #pragma unroll
    for (int j = 0; j < 12; ++j) {
        float v = p1t[n*12 + j] + acc1[n*12 + j] * inv + b1[j];
        h1[j] = v > 0.f ? v : 0.f;
    }
    #pragma unroll
    for (int co = 0; co < 12; ++co) {
        float a = 0.f, b = 0.f;
        #pragma unroll
        for (int k = 0; k < 12; ++k) {
            a += h1[k] * w2[k*12 + co];
            b += h1[k] * w2[(12+k)*12 + co];
        }
        p2t[n*12 + co] = a;
        p2b[n*12 + co] = b;
    }
}

// ---------------- finalize layer2 + graph pooling ------------------------------
__global__ void finalize2_kernel(const float* __restrict__ p2t, const float* __restrict__ acc2,
                                 const int* __restrict__ deg, const float* __restrict__ b2eff,
                                 const int* __restrict__ graph_id,
                                 float* __restrict__ accg, float* __restrict__ cntg) {
    __shared__ float b2[12];
    if (threadIdx.x < 12) b2[threadIdx.x] = b2eff[threadIdx.x];
    __syncthreads();
    int n = blockIdx.x * blockDim.x + threadIdx.x;
    if (n >= NN) return;
    int dg = deg[n];
    float inv = dg > 0 ? 1.f / (float)dg : 0.f;
    int g = graph_id[n];
    #pragma unroll
    for (int j = 0; j < 12; ++j) {
        float v = p2t[n*12 + j] + acc2[n*12 + j] * inv + b2[j];
        v = v > 0.f ? v : 0.f;
        atomicAdd(&accg[g*12 + j], v);
    }
    atomicAdd(&cntg[g], 1.0f);
}

// ---------------- output: hg @ Wc + bc -----------------------------------------
__global__ void out_kernel(const float* __restrict__ accg, const float* __restrict__ cntg,
                           const float* __restrict__ Wc, const float* __restrict__ bc,
                           float* __restrict__ out) {
    int t = blockIdx.x * blockDim.x + threadIdx.x;
    if (t >= NG * 10) return;
    int g = t / 10, cls = t - g * 10;
    float c = cntg[g];
    float inv = c > 0.f ? 1.f / c : 0.f;
    float acc = bc[cls];
    #pragma unroll
    for (int j = 0; j < 12; ++j) acc += accg[g*12 + j] * inv * Wc[j*10 + cls];
    out[t] = acc;
}

extern "C" void kernel_launch(void* const* d_in, const int* in_sizes, int n_in,
                              void* d_out, int out_size, void* d_ws, size_t ws_size,
                              hipStream_t stream) {
    const float* h   = (const float*)d_in[0];
    const int* src   = (const int*)d_in[1];
    const int* dst   = (const int*)d_in[2];
    const int* gid   = (const int*)d_in[3];
    const float* W1a = (const float*)d_in[4];
    const float* b1a = (const float*)d_in[5];
    const float* W1b = (const float*)d_in[6];
    const float* b1b = (const float*)d_in[7];
    const float* W2a = (const float*)d_in[8];
    const float* b2a = (const float*)d_in[9];
    const float* W2b = (const float*)d_in[10];
    const float* b2b = (const float*)d_in[11];
    const float* Wc  = (const float*)d_in[12];
    const float* bc  = (const float*)d_in[13];
    float* out = (float*)d_out;

    float* ws = (float*)d_ws;
    float* W1eff = ws;                    // 3072
    float* b1eff = ws + 3072;             // 12
    float* W2eff = ws + 3084;             // 288
    float* b2eff = ws + 3372;             // 12 -> 3384
    float* p1t   = ws + 3384;             // 600000
    float* p1b   = ws + 603384;           // 600000
    float* p2t   = ws + 1203384;          // 600000
    float* p2b   = ws + 1803384;          // 600000
    float* acc1  = ws + 2403384;          // 600000 (written directly, no zero needed)
    float* acc2  = ws + 3003384;          // 600000
    // ---- zeroed region (accg, cntg, deg, cursor contiguous) ----
    float* accg  = ws + 3603384;          // 6144
    float* cntg  = ws + 3609528;          // 512
    int*   deg        = (int*)(ws + 3610040);   // 50000
    int*   cursor     = (int*)(ws + 3660040);   // 50000
    // ---- end zeroed region ----
    int*   row_start  = (int*)(ws + 3710040);   // 50001
    int*   bsums      = (int*)(ws + 3760041);   // 196
    int*   boffs      = (int*)(ws + 3760237);   // 196
    int*   sorted_src = (int*)(ws + 3760433);   // 800000

    hipMemsetAsync(accg, 0, (size_t)(6144 + 512 + 50000 + 50000) * sizeof(float), stream);

    fold_kernel<<<14, 256, 0, stream>>>(W1a, b1a, W1b, b1b, W2a, b2a, W2b, b2b,
                                        W1eff, b1eff, W2eff, b2eff);

    p1_kernel<<<(NN + 15) / 16, 256, 0, stream>>>(h, W1eff, p1t, p1b);

    deg_kernel<<<(NE + 255) / 256, 256, 0, stream>>>(dst, deg);
    bsum_kernel<<<SCAN_BLOCKS, 256, 0, stream>>>(deg, bsums);
    bscan_kernel<<<1, 256, 0, stream>>>(bsums, boffs);
    rowscan_kernel<<<SCAN_BLOCKS, 256, 0, stream>>>(deg, boffs, row_start);
    scatter_kernel<<<(NE + 255) / 256, 256, 0, stream>>>(src, dst, row_start, cursor, sorted_src);

    gather_kernel<<<(NN * 12 + 255) / 256, 256, 0, stream>>>(row_start, sorted_src, p1b, acc1);
    finalize1_kernel<<<(NN + 255) / 256, 256, 0, stream>>>(p1t, acc1, deg, b1eff, W2eff, p2t, p2b);

    gather_kernel<<<(NN * 12 + 255) / 256, 256, 0, stream>>>(row_start, sorted_src, p2b, acc2);
    finalize2_kernel<<<(NN + 255) / 256, 256, 0, stream>>>(p2t, acc2, deg, b2eff, gid, accg, cntg);

    out_kernel<<<(NG * 10 + 255) / 256, 256, 0, stream>>>(accg, cntg, Wc, bc, out);
}

// Round 4
// 206.830 us; speedup vs baseline: 1.7504x; 1.2808x over previous
//
#include <hip/hip_runtime.h>
#include <hip/hip_bf16.h>

#define NN 50000
#define NE 800000
#define NG 512
#define IND 128
#define MIDD 12
#define SCAN_BLOCKS 196   // 196*256 = 50176 >= NN+1

// ---------------- fold weights: W1eff=[256,12], b1eff, W2eff=[24,12], b2eff ----
__global__ void fold_kernel(const float* __restrict__ W1a, const float* __restrict__ b1a,
                            const float* __restrict__ W1b, const float* __restrict__ b1b,
                            const float* __restrict__ W2a, const float* __restrict__ b2a,
                            const float* __restrict__ W2b, const float* __restrict__ b2b,
                            float* __restrict__ W1eff, float* __restrict__ b1eff,
                            float* __restrict__ W2eff, float* __restrict__ b2eff) {
    int t = blockIdx.x * blockDim.x + threadIdx.x;
    if (t < 3072) {
        int r = t / 12, c = t % 12;
        float acc = 0.f;
        for (int k = 0; k < 256; ++k) acc += W1a[r*256 + k] * W1b[k*12 + c];
        W1eff[r*12 + c] = acc;
    } else if (t < 3084) {
        int c = t - 3072;
        float acc = b1b[c];
        for (int k = 0; k < 256; ++k) acc += b1a[k] * W1b[k*12 + c];
        b1eff[c] = acc;
    } else if (t < 3372) {
        int u = t - 3084;
        int r = u / 12, c = u % 12;
        float acc = 0.f;
        for (int k = 0; k < 256; ++k) acc += W2a[r*256 + k] * W2b[k*12 + c];
        W2eff[r*12 + c] = acc;
    } else if (t < 3384) {
        int c = t - 3372;
        float acc = b2b[c];
        for (int k = 0; k < 256; ++k) acc += b2a[k] * W2b[k*12 + c];
        b2eff[c] = acc;
    }
}

// ---------------- p1: h [NN,128] @ W1eff -> p1_top [NN,12], p1_bot [NN,12] -----
__global__ void p1_kernel(const float* __restrict__ h, const float* __restrict__ W1eff,
                          float* __restrict__ p1t, float* __restrict__ p1b) {
    __shared__ float wsm[256 * 12];
    __shared__ float hs[16 * 129];
    int tid = threadIdx.x;
    for (int i = tid; i < 3072; i += 256) wsm[i] = W1eff[i];
    int node0 = blockIdx.x * 16;
    for (int i = tid; i < 16 * 128; i += 256) {
        int nl = i >> 7, k = i & 127;
        int n = node0 + nl;
        hs[nl * 129 + k] = (n < NN) ? h[n * 128 + k] : 0.0f;
    }
    __syncthreads();
    for (int idx = tid; idx < 16 * 24; idx += 256) {
        int nl = idx / 24, c = idx % 24;
        int n = node0 + nl;
        if (n >= NN) continue;
        const float* hrow = &hs[nl * 129];
        float acc = 0.f;
        if (c < 12) {
            #pragma unroll
            for (int k = 0; k < 128; ++k) acc += hrow[k] * wsm[k*12 + c];
            p1t[n*12 + c] = acc;
        } else {
            int cc = c - 12;
            #pragma unroll
            for (int k = 0; k < 128; ++k) acc += hrow[k] * wsm[(128+k)*12 + cc];
            p1b[n*12 + cc] = acc;
        }
    }
}

// ---------------- CSR build: deg histogram -------------------------------------
__global__ void deg_kernel(const int* __restrict__ dst, int* __restrict__ deg) {
    int e = blockIdx.x * blockDim.x + threadIdx.x;
    if (e >= NE) return;
    atomicAdd(&deg[dst[e]], 1);
}

// ---------------- parallel scan stage 1: per-block sums ------------------------
__global__ void bsum_kernel(const int* __restrict__ deg, int* __restrict__ bsums) {
    __shared__ int sh[256];
    int tid = threadIdx.x;
    int i = blockIdx.x * 256 + tid;
    sh[tid] = (i < NN) ? deg[i] : 0;
    __syncthreads();
    for (int off = 128; off > 0; off >>= 1) {
        if (tid < off) sh[tid] += sh[tid + off];
        __syncthreads();
    }
    if (tid == 0) bsums[blockIdx.x] = sh[0];
}

// ---------------- parallel scan stage 2: scan block sums (1 block) -------------
__global__ void bscan_kernel(const int* __restrict__ bsums, int* __restrict__ boffs) {
    __shared__ int sh[256];
    int tid = threadIdx.x;
    int v = (tid < SCAN_BLOCKS) ? bsums[tid] : 0;
    sh[tid] = v;
    __syncthreads();
    for (int off = 1; off < 256; off <<= 1) {
        int t = (tid >= off) ? sh[tid - off] : 0;
        __syncthreads();
        sh[tid] += t;
        __syncthreads();
    }
    if (tid < SCAN_BLOCKS) boffs[tid] = sh[tid] - v;  // exclusive
}

// ---------------- parallel scan stage 3: per-block exclusive scan + write ------
__global__ void rowscan_kernel(const int* __restrict__ deg, const int* __restrict__ boffs,
                               int* __restrict__ row_start) {
    __shared__ int sh[256];
    int tid = threadIdx.x;
    int i = blockIdx.x * 256 + tid;
    int v = (i < NN) ? deg[i] : 0;
    sh[tid] = v;
    __syncthreads();
    for (int off = 1; off < 256; off <<= 1) {
        int t = (tid >= off) ? sh[tid - off] : 0;
        __syncthreads();
        sh[tid] += t;
        __syncthreads();
    }
    if (i <= NN) row_start[i] = boffs[blockIdx.x] + sh[tid] - v;
}

// ---------------- CSR build: scatter src into buckets --------------------------
__global__ void scatter_kernel(const int* __restrict__ src, const int* __restrict__ dst,
                               const int* __restrict__ row_start, int* __restrict__ cursor,
                               int* __restrict__ sorted_src) {
    int e = blockIdx.x * blockDim.x + threadIdx.x;
    if (e >= NE) return;
    int d = dst[e];
    int pos = row_start[d] + atomicAdd(&cursor[d], 1);
    sorted_src[pos] = src[e];
}

// ---------------- gather: acc[n,c] = sum over in-edges of p[src,c] -------------
__global__ void gather_kernel(const int* __restrict__ row_start, const int* __restrict__ sorted_src,
                              const float* __restrict__ p, float* __restrict__ acc) {
    int t = blockIdx.x * blockDim.x + threadIdx.x;
    if (t >= NN * 12) return;
    int n = t / 12, c = t - n * 12;
    int r0 = row_start[n], r1 = row_start[n + 1];
    float s = 0.f;
    if (r0 < r1) {
        int sn = sorted_src[r0];                 // software-pipelined: next index
        for (int i = r0 + 1; i < r1; ++i) {
            int sn_next = sorted_src[i];
            s += p[sn * 12 + c];
            sn = sn_next;
        }
        s += p[sn * 12 + c];
    }
    acc[t] = s;
}

// ---------------- finalize layer1 + compute p2_top/p2_bot ----------------------
__global__ void finalize1_kernel(const float* __restrict__ p1t, const float* __restrict__ acc1,
                                 const int* __restrict__ deg, const float* __restrict__ b1eff,
                                 const float* __restrict__ W2eff,
                                 float* __restrict__ p2t, float* __restrict__ p2b) {
    __shared__ float w2[288];
    __shared__ float b1[12];
    int tid = threadIdx.x;
    for (int i = tid; i < 288; i += 256) w2[i] = W2eff[i];
    if (tid < 12) b1[tid] = b1eff[tid];
    __syncthreads();
    int n = blockIdx.x * blockDim.x + tid;
    if (n >= NN) return;
    int dg = deg[n];
    float inv = dg > 0 ? 1.f / (float)dg : 0.f;
    float h1[12];
    #pragma unroll
    for (int j = 0; j < 12; ++j) {
        float v = p1t[n*12 + j] + acc1[n*12 + j] * inv + b1[j];
        h1[j] = v > 0.f ? v : 0.f;
    }
    #pragma unroll
    for (int co = 0; co < 12; ++co) {
        float a = 0.f, b = 0.f;
        #pragma unroll
        for (int k = 0; k < 12; ++k) {
            a += h1[k] * w2[k*12 + co];
            b += h1[k] * w2[(12+k)*12 + co];
        }
        p2t[n*12 + co] = a;
        p2b[n*12 + co] = b;
    }
}

// ---------------- graph boundaries from sorted graph_id ------------------------
__global__ void gstart_kernel(const int* __restrict__ gid, int* __restrict__ gstart) {
    int n = blockIdx.x * blockDim.x + threadIdx.x;
    if (n >= NN) return;
    int cur = gid[n];
    int prev = (n == 0) ? -1 : gid[n - 1];
    for (int g = prev + 1; g <= cur; ++g) gstart[g] = n;   // first node with gid >= g
    if (n == NN - 1) {
        for (int g = cur + 1; g <= NG; ++g) gstart[g] = NN;
    }
}

// ---------------- per-graph: finalize2 + segment mean + @Wc + bc ---------------
__global__ void graph_kernel(const float* __restrict__ p2t, const float* __restrict__ acc2,
                             const int* __restrict__ deg, const int* __restrict__ gstart,
                             const float* __restrict__ b2eff, const float* __restrict__ Wc,
                             const float* __restrict__ bc, float* __restrict__ out) {
    __shared__ float sh[252];   // 21 groups x 12 channels
    __shared__ float hg[12];
    int g = blockIdx.x;
    int r0 = gstart[g], r1 = gstart[g + 1];
    int tid = threadIdx.x;
    int group = tid / 12, ch = tid - group * 12;   // valid for tid < 252
    if (tid < 252) {
        float b2 = b2eff[ch];
        float s = 0.f;
        for (int n = r0 + group; n < r1; n += 21) {
            int dg = deg[n];
            float inv = dg > 0 ? 1.f / (float)dg : 0.f;
            float v = p2t[n*12 + ch] + acc2[n*12 + ch] * inv + b2;
            s += v > 0.f ? v : 0.f;
        }
        sh[tid] = s;
    }
    __syncthreads();
    if (tid < 12) {
        float tot = 0.f;
        #pragma unroll
        for (int k = 0; k < 21; ++k) tot += sh[k*12 + tid];
        int cnt = r1 - r0;
        hg[tid] = cnt > 0 ? tot / (float)cnt : 0.f;
    }
    __syncthreads();
    if (tid < 10) {
        float o = bc[tid];
        #pragma unroll
        for (int j = 0; j < 12; ++j) o += hg[j] * Wc[j*10 + tid];
        out[g*10 + tid] = o;
    }
}

extern "C" void kernel_launch(void* const* d_in, const int* in_sizes, int n_in,
                              void* d_out, int out_size, void* d_ws, size_t ws_size,
                              hipStream_t stream) {
    const float* h   = (const float*)d_in[0];
    const int* src   = (const int*)d_in[1];
    const int* dst   = (const int*)d_in[2];
    const int* gid   = (const int*)d_in[3];
    const float* W1a = (const float*)d_in[4];
    const float* b1a = (const float*)d_in[5];
    const float* W1b = (const float*)d_in[6];
    const float* b1b = (const float*)d_in[7];
    const float* W2a = (const float*)d_in[8];
    const float* b2a = (const float*)d_in[9];
    const float* W2b = (const float*)d_in[10];
    const float* b2b = (const float*)d_in[11];
    const float* Wc  = (const float*)d_in[12];
    const float* bc  = (const float*)d_in[13];
    float* out = (float*)d_out;

    float* ws = (float*)d_ws;
    float* W1eff = ws;                    // 3072
    float* b1eff = ws + 3072;             // 12
    float* W2eff = ws + 3084;             // 288
    float* b2eff = ws + 3372;             // 12 -> 3384
    float* p1t   = ws + 3384;             // 600000
    float* p1b   = ws + 603384;           // 600000
    float* p2t   = ws + 1203384;          // 600000
    float* p2b   = ws + 1803384;          // 600000
    float* acc1  = ws + 2403384;          // 600000 (written directly, no zero needed)
    float* acc2  = ws + 3003384;          // 600000
    // ---- zeroed region (deg, cursor contiguous) ----
    int*   deg        = (int*)(ws + 3603384);   // 50000
    int*   cursor     = (int*)(ws + 3653384);   // 50000
    // ---- end zeroed region ----
    int*   row_start  = (int*)(ws + 3703384);   // 50001
    int*   bsums      = (int*)(ws + 3753385);   // 196
    int*   boffs      = (int*)(ws + 3753581);   // 196
    int*   gstart     = (int*)(ws + 3753777);   // 513
    int*   sorted_src = (int*)(ws + 3754290);   // 800000

    hipMemsetAsync(deg, 0, (size_t)(50000 + 50000) * sizeof(int), stream);

    fold_kernel<<<14, 256, 0, stream>>>(W1a, b1a, W1b, b1b, W2a, b2a, W2b, b2b,
                                        W1eff, b1eff, W2eff, b2eff);

    p1_kernel<<<(NN + 15) / 16, 256, 0, stream>>>(h, W1eff, p1t, p1b);

    deg_kernel<<<(NE + 255) / 256, 256, 0, stream>>>(dst, deg);
    bsum_kernel<<<SCAN_BLOCKS, 256, 0, stream>>>(deg, bsums);
    bscan_kernel<<<1, 256, 0, stream>>>(bsums, boffs);
    rowscan_kernel<<<SCAN_BLOCKS, 256, 0, stream>>>(deg, boffs, row_start);
    scatter_kernel<<<(NE + 255) / 256, 256, 0, stream>>>(src, dst, row_start, cursor, sorted_src);

    gstart_kernel<<<(NN + 255) / 256, 256, 0, stream>>>(gid, gstart);

    gather_kernel<<<(NN * 12 + 255) / 256, 256, 0, stream>>>(row_start, sorted_src, p1b, acc1);
    finalize1_kernel<<<(NN + 255) / 256, 256, 0, stream>>>(p1t, acc1, deg, b1eff, W2eff, p2t, p2b);

    gather_kernel<<<(NN * 12 + 255) / 256, 256, 0, stream>>>(row_start, sorted_src, p2b, acc2);

    graph_kernel<<<NG, 256, 0, stream>>>(p2t, acc2, deg, gstart, b2eff, Wc, bc, out);
}

// Round 5
// 202.896 us; speedup vs baseline: 1.7843x; 1.0194x over previous
//
#include <hip/hip_runtime.h>
#include <hip/hip_bf16.h>

#define NN 50000
#define NE 800000
#define NG 512
#define IND 128
#define MIDD 12
#define SCAN_BLOCKS 196   // 196*256 = 50176 >= NN+1
#define NB 196            // coarse buckets: dst>>8, 256 nodes each
#define B1_CHUNK 2048
#define B1_BLOCKS ((NE + B1_CHUNK - 1) / B1_CHUNK)   // 391

// ---------------- fold weights: W1eff=[256,12], b1eff, W2eff=[24,12], b2eff ----
__global__ void fold_kernel(const float* __restrict__ W1a, const float* __restrict__ b1a,
                            const float* __restrict__ W1b, const float* __restrict__ b1b,
                            const float* __restrict__ W2a, const float* __restrict__ b2a,
                            const float* __restrict__ W2b, const float* __restrict__ b2b,
                            float* __restrict__ W1eff, float* __restrict__ b1eff,
                            float* __restrict__ W2eff, float* __restrict__ b2eff) {
    int t = blockIdx.x * blockDim.x + threadIdx.x;
    if (t < 3072) {
        int r = t / 12, c = t % 12;
        float acc = 0.f;
        for (int k = 0; k < 256; ++k) acc += W1a[r*256 + k] * W1b[k*12 + c];
        W1eff[r*12 + c] = acc;
    } else if (t < 3084) {
        int c = t - 3072;
        float acc = b1b[c];
        for (int k = 0; k < 256; ++k) acc += b1a[k] * W1b[k*12 + c];
        b1eff[c] = acc;
    } else if (t < 3372) {
        int u = t - 3084;
        int r = u / 12, c = u % 12;
        float acc = 0.f;
        for (int k = 0; k < 256; ++k) acc += W2a[r*256 + k] * W2b[k*12 + c];
        W2eff[r*12 + c] = acc;
    } else if (t < 3384) {
        int c = t - 3372;
        float acc = b2b[c];
        for (int k = 0; k < 256; ++k) acc += b2a[k] * W2b[k*12 + c];
        b2eff[c] = acc;
    }
}

// ---------------- p1: h [NN,128] @ W1eff -> p1_top [NN,12], p1_bot [NN,12] -----
__global__ void p1_kernel(const float* __restrict__ h, const float* __restrict__ W1eff,
                          float* __restrict__ p1t, float* __restrict__ p1b) {
    __shared__ float wsm[256 * 12];
    __shared__ float hs[16 * 129];
    int tid = threadIdx.x;
    for (int i = tid; i < 3072; i += 256) wsm[i] = W1eff[i];
    int node0 = blockIdx.x * 16;
    for (int i = tid; i < 16 * 128; i += 256) {
        int nl = i >> 7, k = i & 127;
        int n = node0 + nl;
        hs[nl * 129 + k] = (n < NN) ? h[n * 128 + k] : 0.0f;
    }
    __syncthreads();
    for (int idx = tid; idx < 16 * 24; idx += 256) {
        int nl = idx / 24, c = idx % 24;
        int n = node0 + nl;
        if (n >= NN) continue;
        const float* hrow = &hs[nl * 129];
        float acc = 0.f;
        if (c < 12) {
            #pragma unroll
            for (int k = 0; k < 128; ++k) acc += hrow[k] * wsm[k*12 + c];
            p1t[n*12 + c] = acc;
        } else {
            int cc = c - 12;
            #pragma unroll
            for (int k = 0; k < 128; ++k) acc += hrow[k] * wsm[(128+k)*12 + cc];
            p1b[n*12 + cc] = acc;
        }
    }
}

// ---------------- CSR build: deg histogram -------------------------------------
__global__ void deg_kernel(const int* __restrict__ dst, int* __restrict__ deg) {
    int e = blockIdx.x * blockDim.x + threadIdx.x;
    if (e >= NE) return;
    atomicAdd(&deg[dst[e]], 1);
}

// ---------------- parallel scan stage 1: per-block sums ------------------------
__global__ void bsum_kernel(const int* __restrict__ deg, int* __restrict__ bsums) {
    __shared__ int sh[256];
    int tid = threadIdx.x;
    int i = blockIdx.x * 256 + tid;
    sh[tid] = (i < NN) ? deg[i] : 0;
    __syncthreads();
    for (int off = 128; off > 0; off >>= 1) {
        if (tid < off) sh[tid] += sh[tid + off];
        __syncthreads();
    }
    if (tid == 0) bsums[blockIdx.x] = sh[0];
}

// ---------------- parallel scan stage 2: scan block sums (1 block) -------------
__global__ void bscan_kernel(const int* __restrict__ bsums, int* __restrict__ boffs) {
    __shared__ int sh[256];
    int tid = threadIdx.x;
    int v = (tid < SCAN_BLOCKS) ? bsums[tid] : 0;
    sh[tid] = v;
    __syncthreads();
    for (int off = 1; off < 256; off <<= 1) {
        int t = (tid >= off) ? sh[tid - off] : 0;
        __syncthreads();
        sh[tid] += t;
        __syncthreads();
    }
    if (tid < SCAN_BLOCKS) boffs[tid] = sh[tid] - v;  // exclusive
}

// ---------------- parallel scan stage 3: per-block exclusive scan + write ------
__global__ void rowscan_kernel(const int* __restrict__ deg, const int* __restrict__ boffs,
                               int* __restrict__ row_start) {
    __shared__ int sh[256];
    int tid = threadIdx.x;
    int i = blockIdx.x * 256 + tid;
    int v = (i < NN) ? deg[i] : 0;
    sh[tid] = v;
    __syncthreads();
    for (int off = 1; off < 256; off <<= 1) {
        int t = (tid >= off) ? sh[tid - off] : 0;
        __syncthreads();
        sh[tid] += t;
        __syncthreads();
    }
    if (i <= NN) row_start[i] = boffs[blockIdx.x] + sh[tid] - v;
}

// ---------------- B1: bucketed scatter of (dst,src) pairs into coarse regions --
__global__ void bucket_scatter_kernel(const int* __restrict__ src, const int* __restrict__ dst,
                                      const int* __restrict__ row_start,
                                      int* __restrict__ bcursor,
                                      unsigned long long* __restrict__ pairs) {
    __shared__ int hist[NB];
    __shared__ int lbase[NB];
    __shared__ int lcur[NB];
    int tid = threadIdx.x;
    for (int i = tid; i < NB; i += 256) hist[i] = 0;
    __syncthreads();
    int e0 = blockIdx.x * B1_CHUNK;
    int d[8];
    #pragma unroll
    for (int k = 0; k < 8; ++k) {
        int e = e0 + tid + k * 256;
        if (e < NE) {
            d[k] = dst[e];
            atomicAdd(&hist[d[k] >> 8], 1);
        } else d[k] = -1;
    }
    __syncthreads();
    for (int b = tid; b < NB; b += 256) {
        int hcnt = hist[b];
        if (hcnt > 0) {
            lbase[b] = row_start[b << 8] + atomicAdd(&bcursor[b], hcnt);
        }
        lcur[b] = 0;
    }
    __syncthreads();
    #pragma unroll
    for (int k = 0; k < 8; ++k) {
        int e = e0 + tid + k * 256;
        if (e < NE) {
            int dd = d[k];
            int ss = src[e];
            int bb = dd >> 8;
            int idx = atomicAdd(&lcur[bb], 1);
            pairs[lbase[bb] + idx] = ((unsigned long long)(unsigned)ss << 32) | (unsigned)dd;
        }
    }
}

// ---------------- B2: place pairs within bucket -> sorted_src ------------------
__global__ void fine_place_kernel(const unsigned long long* __restrict__ pairs,
                                  const int* __restrict__ row_start,
                                  int* __restrict__ sorted_src) {
    __shared__ int rs[257];
    __shared__ int cnt[256];
    int tid = threadIdx.x;
    int b = blockIdx.x;
    int n0 = b << 8;
    int n1 = min(n0 + 256, NN);
    int nloc = n1 - n0;
    for (int i = tid; i <= nloc; i += 256) rs[i] = row_start[n0 + i];
    cnt[tid] = 0;
    __syncthreads();
    int R0 = rs[0], R1 = rs[nloc];
    for (int i = R0 + tid; i < R1; i += 256) {
        unsigned long long pr = pairs[i];
        int dd = (int)(pr & 0xffffffffULL);
        int ss = (int)(pr >> 32);
        int ln = dd - n0;
        int off = atomicAdd(&cnt[ln], 1);
        sorted_src[rs[ln] + off] = ss;
    }
}

// ---------------- gather: acc[n,c] = sum over in-edges of p[src,c] -------------
__global__ void gather_kernel(const int* __restrict__ row_start, const int* __restrict__ sorted_src,
                              const float* __restrict__ p, float* __restrict__ acc) {
    int t = blockIdx.x * blockDim.x + threadIdx.x;
    if (t >= NN * 12) return;
    int n = t / 12, c = t - n * 12;
    int r0 = row_start[n], r1 = row_start[n + 1];
    float s = 0.f;
    if (r0 < r1) {
        int sn = sorted_src[r0];                 // software-pipelined prefetch
        for (int i = r0 + 1; i < r1; ++i) {
            int sn_next = sorted_src[i];
            s += p[sn * 12 + c];
            sn = sn_next;
        }
        s += p[sn * 12 + c];
    }
    acc[t] = s;
}

// ---------------- finalize layer1 + compute p2_top/p2_bot ----------------------
__global__ void finalize1_kernel(const float* __restrict__ p1t, const float* __restrict__ acc1,
                                 const int* __restrict__ deg, const float* __restrict__ b1eff,
                                 const float* __restrict__ W2eff,
                                 float* __restrict__ p2t, float* __restrict__ p2b) {
    __shared__ float w2[288];
    __shared__ float b1[12];
    int tid = threadIdx.x;
    for (int i = tid; i < 288; i += 256) w2[i] = W2eff[i];
    if (tid < 12) b1[tid] = b1eff[tid];
    __syncthreads();
    int n = blockIdx.x * blockDim.x + tid;
    if (n >= NN) return;
    int dg = deg[n];
    float inv = dg > 0 ? 1.f / (float)dg : 0.f;
    float h1[12];
    #pragma unroll
    for (int j = 0; j < 12; ++j) {
        float v = p1t[n*12 + j] + acc1[n*12 + j] * inv + b1[j];
        h1[j] = v > 0.f ? v : 0.f;
    }
    #pragma unroll
    for (int co = 0; co < 12; ++co) {
        float a = 0.f, b = 0.f;
        #pragma unroll
        for (int k = 0; k < 12; ++k) {
            a += h1[k] * w2[k*12 + co];
            b += h1[k] * w2[(12+k)*12 + co];
        }
        p2t[n*12 + co] = a;
        p2b[n*12 + co] = b;
    }
}

// ---------------- graph boundaries from sorted graph_id ------------------------
__global__ void gstart_kernel(const int* __restrict__ gid, int* __restrict__ gstart) {
    int n = blockIdx.x * blockDim.x + threadIdx.x;
    if (n >= NN) return;
    int cur = gid[n];
    int prev = (n == 0) ? -1 : gid[n - 1];
    for (int g = prev + 1; g <= cur; ++g) gstart[g] = n;
    if (n == NN - 1) {
        for (int g = cur + 1; g <= NG; ++g) gstart[g] = NN;
    }
}

// ---------------- per-graph: finalize2 + segment mean + @Wc + bc ---------------
__global__ void graph_kernel(const float* __restrict__ p2t, const float* __restrict__ acc2,
                             const int* __restrict__ deg, const int* __restrict__ gstart,
                             const float* __restrict__ b2eff, const float* __restrict__ Wc,
                             const float* __restrict__ bc, float* __restrict__ out) {
    __shared__ float sh[252];
    __shared__ float hg[12];
    int g = blockIdx.x;
    int r0 = gstart[g], r1 = gstart[g + 1];
    int tid = threadIdx.x;
    int group = tid / 12, ch = tid - group * 12;
    if (tid < 252) {
        float b2 = b2eff[ch];
        float s = 0.f;
        for (int n = r0 + group; n < r1; n += 21) {
            int dg = deg[n];
            float inv = dg > 0 ? 1.f / (float)dg : 0.f;
            float v = p2t[n*12 + ch] + acc2[n*12 + ch] * inv + b2;
            s += v > 0.f ? v : 0.f;
        }
        sh[tid] = s;
    }
    __syncthreads();
    if (tid < 12) {
        float tot = 0.f;
        #pragma unroll
        for (int k = 0; k < 21; ++k) tot += sh[k*12 + tid];
        int cntn = r1 - r0;
        hg[tid] = cntn > 0 ? tot / (float)cntn : 0.f;
    }
    __syncthreads();
    if (tid < 10) {
        float o = bc[tid];
        #pragma unroll
        for (int j = 0; j < 12; ++j) o += hg[j] * Wc[j*10 + tid];
        out[g*10 + tid] = o;
    }
}

extern "C" void kernel_launch(void* const* d_in, const int* in_sizes, int n_in,
                              void* d_out, int out_size, void* d_ws, size_t ws_size,
                              hipStream_t stream) {
    const float* h   = (const float*)d_in[0];
    const int* src   = (const int*)d_in[1];
    const int* dst   = (const int*)d_in[2];
    const int* gid   = (const int*)d_in[3];
    const float* W1a = (const float*)d_in[4];
    const float* b1a = (const float*)d_in[5];
    const float* W1b = (const float*)d_in[6];
    const float* b1b = (const float*)d_in[7];
    const float* W2a = (const float*)d_in[8];
    const float* b2a = (const float*)d_in[9];
    const float* W2b = (const float*)d_in[10];
    const float* b2b = (const float*)d_in[11];
    const float* Wc  = (const float*)d_in[12];
    const float* bc  = (const float*)d_in[13];
    float* out = (float*)d_out;

    float* ws = (float*)d_ws;
    float* W1eff = ws;                    // 3072
    float* b1eff = ws + 3072;             // 12
    float* W2eff = ws + 3084;             // 288
    float* b2eff = ws + 3372;             // 12 -> 3384
    float* p1t   = ws + 3384;             // 600000
    float* p1b   = ws + 603384;           // 600000
    float* p2t   = ws + 1203384;          // 600000
    float* p2b   = ws + 1803384;          // 600000
    float* acc1  = ws + 2403384;          // 600000
    float* acc2  = ws + 3003384;          // 600000 -> 3603384
    // pairs (6.4 MB) aliased over p2t/p2b/acc1 — dead during CSR build,
    // B2 completes before gather/finalize write them.
    unsigned long long* pairs = (unsigned long long*)(ws + 1203384);   // 800000 x 8B
    // ---- zeroed region (deg, bcursor contiguous) ----
    int*   deg        = (int*)(ws + 3603384);   // 50000
    int*   bcursor    = (int*)(ws + 3653384);   // 196
    // ---- end zeroed region ----
    int*   row_start  = (int*)(ws + 3653580);   // 50001
    int*   bsums      = (int*)(ws + 3703581);   // 196
    int*   boffs      = (int*)(ws + 3703777);   // 196
    int*   gstart     = (int*)(ws + 3703973);   // 513
    int*   sorted_src = (int*)(ws + 3704486);   // 800000 -> 4504486 floats (~18 MB)

    hipMemsetAsync(deg, 0, (size_t)(50000 + 196) * sizeof(int), stream);

    fold_kernel<<<14, 256, 0, stream>>>(W1a, b1a, W1b, b1b, W2a, b2a, W2b, b2b,
                                        W1eff, b1eff, W2eff, b2eff);

    deg_kernel<<<(NE + 255) / 256, 256, 0, stream>>>(dst, deg);
    bsum_kernel<<<SCAN_BLOCKS, 256, 0, stream>>>(deg, bsums);
    bscan_kernel<<<1, 256, 0, stream>>>(bsums, boffs);
    rowscan_kernel<<<SCAN_BLOCKS, 256, 0, stream>>>(deg, boffs, row_start);

    bucket_scatter_kernel<<<B1_BLOCKS, 256, 0, stream>>>(src, dst, row_start, bcursor, pairs);
    fine_place_kernel<<<NB, 256, 0, stream>>>(pairs, row_start, sorted_src);

    gstart_kernel<<<(NN + 255) / 256, 256, 0, stream>>>(gid, gstart);

    p1_kernel<<<(NN + 15) / 16, 256, 0, stream>>>(h, W1eff, p1t, p1b);

    gather_kernel<<<(NN * 12 + 255) / 256, 256, 0, stream>>>(row_start, sorted_src, p1b, acc1);
    finalize1_kernel<<<(NN + 255) / 256, 256, 0, stream>>>(p1t, acc1, deg, b1eff, W2eff, p2t, p2b);

    gather_kernel<<<(NN * 12 + 255) / 256, 256, 0, stream>>>(row_start, sorted_src, p2b, acc2);

    graph_kernel<<<NG, 256, 0, stream>>>(p2t, acc2, deg, gstart, b2eff, Wc, bc, out);
}

// Round 6
// 179.928 us; speedup vs baseline: 2.0121x; 1.1277x over previous
//
#include <hip/hip_runtime.h>
#include <hip/hip_bf16.h>

#define NN 50000
#define NE 800000
#define NG 512
#define IND 128
#define MIDD 12
#define SCAN_BLOCKS 196   // 196*256 = 50176 >= NN+1
#define NB 196            // coarse buckets: dst>>8, 256 nodes each
#define B1_CHUNK 2048
#define B1_BLOCKS ((NE + B1_CHUNK - 1) / B1_CHUNK)   // 391

// ---------------- fold weights: W1eff=[256,12], b1eff, W2eff=[24,12], b2eff ----
__global__ void fold_kernel(const float* __restrict__ W1a, const float* __restrict__ b1a,
                            const float* __restrict__ W1b, const float* __restrict__ b1b,
                            const float* __restrict__ W2a, const float* __restrict__ b2a,
                            const float* __restrict__ W2b, const float* __restrict__ b2b,
                            float* __restrict__ W1eff, float* __restrict__ b1eff,
                            float* __restrict__ W2eff, float* __restrict__ b2eff) {
    int t = blockIdx.x * blockDim.x + threadIdx.x;
    if (t < 3072) {
        int r = t / 12, c = t % 12;
        float acc = 0.f;
        for (int k = 0; k < 256; ++k) acc += W1a[r*256 + k] * W1b[k*12 + c];
        W1eff[r*12 + c] = acc;
    } else if (t < 3084) {
        int c = t - 3072;
        float acc = b1b[c];
        for (int k = 0; k < 256; ++k) acc += b1a[k] * W1b[k*12 + c];
        b1eff[c] = acc;
    } else if (t < 3372) {
        int u = t - 3084;
        int r = u / 12, c = u % 12;
        float acc = 0.f;
        for (int k = 0; k < 256; ++k) acc += W2a[r*256 + k] * W2b[k*12 + c];
        W2eff[r*12 + c] = acc;
    } else if (t < 3384) {
        int c = t - 3372;
        float acc = b2b[c];
        for (int k = 0; k < 256; ++k) acc += b2a[k] * W2b[k*12 + c];
        b2eff[c] = acc;
    }
}

// ---------------- p1: h [NN,128] @ W1eff -> p1_top [NN,12], p1_bot [NN,12] -----
// One thread per node. h via 32 aligned float4 loads; W rows (48B each, always
// 16B-aligned) via float4 loads with wave-uniform addresses (L1-hot, 12.25KB).
// 24 independent accumulator chains give the ILP; no LDS at all.
__global__ void p1_kernel(const float* __restrict__ h, const float* __restrict__ W1eff,
                          float* __restrict__ p1t, float* __restrict__ p1b) {
    int n = blockIdx.x * blockDim.x + threadIdx.x;
    if (n >= NN) return;
    const float4* hrow = (const float4*)(h + (size_t)n * 128);
    float acc[24];
    #pragma unroll
    for (int j = 0; j < 24; ++j) acc[j] = 0.f;
    #pragma unroll 4
    for (int kq = 0; kq < 32; ++kq) {
        float4 hv = hrow[kq];
        #pragma unroll
        for (int u = 0; u < 4; ++u) {
            int k = kq * 4 + u;
            float hx = u == 0 ? hv.x : (u == 1 ? hv.y : (u == 2 ? hv.z : hv.w));
            const float4* wt = (const float4*)(W1eff + k * 12);          // 3 float4
            const float4* wb = (const float4*)(W1eff + (128 + k) * 12);  // 3 float4
            #pragma unroll
            for (int q = 0; q < 3; ++q) {
                float4 a = wt[q];
                float4 b = wb[q];
                acc[q*4 + 0]      += hx * a.x;
                acc[q*4 + 1]      += hx * a.y;
                acc[q*4 + 2]      += hx * a.z;
                acc[q*4 + 3]      += hx * a.w;
                acc[12 + q*4 + 0] += hx * b.x;
                acc[12 + q*4 + 1] += hx * b.y;
                acc[12 + q*4 + 2] += hx * b.z;
                acc[12 + q*4 + 3] += hx * b.w;
            }
        }
    }
    float* pt = p1t + (size_t)n * 12;
    float* pb = p1b + (size_t)n * 12;
    #pragma unroll
    for (int c = 0; c < 12; ++c) pt[c] = acc[c];
    #pragma unroll
    for (int c = 0; c < 12; ++c) pb[c] = acc[12 + c];
}

// ---------------- CSR build: deg histogram -------------------------------------
__global__ void deg_kernel(const int* __restrict__ dst, int* __restrict__ deg) {
    int e = blockIdx.x * blockDim.x + threadIdx.x;
    if (e >= NE) return;
    atomicAdd(&deg[dst[e]], 1);
}

// ---------------- parallel scan stage 1: per-block sums ------------------------
__global__ void bsum_kernel(const int* __restrict__ deg, int* __restrict__ bsums) {
    __shared__ int sh[256];
    int tid = threadIdx.x;
    int i = blockIdx.x * 256 + tid;
    sh[tid] = (i < NN) ? deg[i] : 0;
    __syncthreads();
    for (int off = 128; off > 0; off >>= 1) {
        if (tid < off) sh[tid] += sh[tid + off];
        __syncthreads();
    }
    if (tid == 0) bsums[blockIdx.x] = sh[0];
}

// ---------------- parallel scan stage 2: scan block sums (1 block) -------------
__global__ void bscan_kernel(const int* __restrict__ bsums, int* __restrict__ boffs) {
    __shared__ int sh[256];
    int tid = threadIdx.x;
    int v = (tid < SCAN_BLOCKS) ? bsums[tid] : 0;
    sh[tid] = v;
    __syncthreads();
    for (int off = 1; off < 256; off <<= 1) {
        int t = (tid >= off) ? sh[tid - off] : 0;
        __syncthreads();
        sh[tid] += t;
        __syncthreads();
    }
    if (tid < SCAN_BLOCKS) boffs[tid] = sh[tid] - v;  // exclusive
}

// ---------------- parallel scan stage 3: per-block exclusive scan + write ------
__global__ void rowscan_kernel(const int* __restrict__ deg, const int* __restrict__ boffs,
                               int* __restrict__ row_start) {
    __shared__ int sh[256];
    int tid = threadIdx.x;
    int i = blockIdx.x * 256 + tid;
    int v = (i < NN) ? deg[i] : 0;
    sh[tid] = v;
    __syncthreads();
    for (int off = 1; off < 256; off <<= 1) {
        int t = (tid >= off) ? sh[tid - off] : 0;
        __syncthreads();
        sh[tid] += t;
        __syncthreads();
    }
    if (i <= NN) row_start[i] = boffs[blockIdx.x] + sh[tid] - v;
}

// ---------------- B1: bucketed scatter of (dst,src) pairs into coarse regions --
__global__ void bucket_scatter_kernel(const int* __restrict__ src, const int* __restrict__ dst,
                                      const int* __restrict__ row_start,
                                      int* __restrict__ bcursor,
                                      unsigned long long* __restrict__ pairs) {
    __shared__ int hist[NB];
    __shared__ int lbase[NB];
    __shared__ int lcur[NB];
    int tid = threadIdx.x;
    for (int i = tid; i < NB; i += 256) hist[i] = 0;
    __syncthreads();
    int e0 = blockIdx.x * B1_CHUNK;
    int d[8];
    #pragma unroll
    for (int k = 0; k < 8; ++k) {
        int e = e0 + tid + k * 256;
        if (e < NE) {
            d[k] = dst[e];
            atomicAdd(&hist[d[k] >> 8], 1);
        } else d[k] = -1;
    }
    __syncthreads();
    for (int b = tid; b < NB; b += 256) {
        int hcnt = hist[b];
        if (hcnt > 0) {
            lbase[b] = row_start[b << 8] + atomicAdd(&bcursor[b], hcnt);
        }
        lcur[b] = 0;
    }
    __syncthreads();
    #pragma unroll
    for (int k = 0; k < 8; ++k) {
        int e = e0 + tid + k * 256;
        if (e < NE) {
            int dd = d[k];
            int ss = src[e];
            int bb = dd >> 8;
            int idx = atomicAdd(&lcur[bb], 1);
            pairs[lbase[bb] + idx] = ((unsigned long long)(unsigned)ss << 32) | (unsigned)dd;
        }
    }
}

// ---------------- B2: place pairs within bucket -> sorted_src ------------------
__global__ void fine_place_kernel(const unsigned long long* __restrict__ pairs,
                                  const int* __restrict__ row_start,
                                  int* __restrict__ sorted_src) {
    __shared__ int rs[257];
    __shared__ int cnt[256];
    int tid = threadIdx.x;
    int b = blockIdx.x;
    int n0 = b << 8;
    int n1 = min(n0 + 256, NN);
    int nloc = n1 - n0;
    for (int i = tid; i <= nloc; i += 256) rs[i] = row_start[n0 + i];
    cnt[tid] = 0;
    __syncthreads();
    int R0 = rs[0], R1 = rs[nloc];
    for (int i = R0 + tid; i < R1; i += 256) {
        unsigned long long pr = pairs[i];
        int dd = (int)(pr & 0xffffffffULL);
        int ss = (int)(pr >> 32);
        int ln = dd - n0;
        int off = atomicAdd(&cnt[ln], 1);
        sorted_src[rs[ln] + off] = ss;
    }
}

// ---------------- gather: acc[n,c] = sum over in-edges of p[src,c] -------------
__global__ void gather_kernel(const int* __restrict__ row_start, const int* __restrict__ sorted_src,
                              const float* __restrict__ p, float* __restrict__ acc) {
    int t = blockIdx.x * blockDim.x + threadIdx.x;
    if (t >= NN * 12) return;
    int n = t / 12, c = t - n * 12;
    int r0 = row_start[n], r1 = row_start[n + 1];
    float s = 0.f;
    if (r0 < r1) {
        int sn = sorted_src[r0];                 // software-pipelined prefetch
        for (int i = r0 + 1; i < r1; ++i) {
            int sn_next = sorted_src[i];
            s += p[sn * 12 + c];
            sn = sn_next;
        }
        s += p[sn * 12 + c];
    }
    acc[t] = s;
}

// ---------------- finalize layer1 + compute p2_top/p2_bot ----------------------
__global__ void finalize1_kernel(const float* __restrict__ p1t, const float* __restrict__ acc1,
                                 const int* __restrict__ deg, const float* __restrict__ b1eff,
                                 const float* __restrict__ W2eff,
                                 float* __restrict__ p2t, float* __restrict__ p2b) {
    __shared__ float w2[288];
    __shared__ float b1[12];
    int tid = threadIdx.x;
    for (int i = tid; i < 288; i += 256) w2[i] = W2eff[i];
    if (tid < 12) b1[tid] = b1eff[tid];
    __syncthreads();
    int n = blockIdx.x * blockDim.x + tid;
    if (n >= NN) return;
    int dg = deg[n];
    float inv = dg > 0 ? 1.f / (float)dg : 0.f;
    float h1[12];
    #pragma unroll
    for (int j = 0; j < 12; ++j) {
        float v = p1t[n*12 + j] + acc1[n*12 + j] * inv + b1[j];
        h1[j] = v > 0.f ? v : 0.f;
    }
    #pragma unroll
    for (int co = 0; co < 12; ++co) {
        float a = 0.f, b = 0.f;
        #pragma unroll
        for (int k = 0; k < 12; ++k) {
            a += h1[k] * w2[k*12 + co];
            b += h1[k] * w2[(12+k)*12 + co];
        }
        p2t[n*12 + co] = a;
        p2b[n*12 + co] = b;
    }
}

// ---------------- graph boundaries from sorted graph_id ------------------------
__global__ void gstart_kernel(const int* __restrict__ gid, int* __restrict__ gstart) {
    int n = blockIdx.x * blockDim.x + threadIdx.x;
    if (n >= NN) return;
    int cur = gid[n];
    int prev = (n == 0) ? -1 : gid[n - 1];
    for (int g = prev + 1; g <= cur; ++g) gstart[g] = n;
    if (n == NN - 1) {
        for (int g = cur + 1; g <= NG; ++g) gstart[g] = NN;
    }
}

// ---------------- per-graph: finalize2 + segment mean + @Wc + bc ---------------
__global__ void graph_kernel(const float* __restrict__ p2t, const float* __restrict__ acc2,
                             const int* __restrict__ deg, const int* __restrict__ gstart,
                             const float* __restrict__ b2eff, const float* __restrict__ Wc,
                             const float* __restrict__ bc, float* __restrict__ out) {
    __shared__ float sh[252];
    __shared__ float hg[12];
    int g = blockIdx.x;
    int r0 = gstart[g], r1 = gstart[g + 1];
    int tid = threadIdx.x;
    int group = tid / 12, ch = tid - group * 12;
    if (tid < 252) {
        float b2 = b2eff[ch];
        float s = 0.f;
        for (int n = r0 + group; n < r1; n += 21) {
            int dg = deg[n];
            float inv = dg > 0 ? 1.f / (float)dg : 0.f;
            float v = p2t[n*12 + ch] + acc2[n*12 + ch] * inv + b2;
            s += v > 0.f ? v : 0.f;
        }
        sh[tid] = s;
    }
    __syncthreads();
    if (tid < 12) {
        float tot = 0.f;
        #pragma unroll
        for (int k = 0; k < 21; ++k) tot += sh[k*12 + tid];
        int cntn = r1 - r0;
        hg[tid] = cntn > 0 ? tot / (float)cntn : 0.f;
    }
    __syncthreads();
    if (tid < 10) {
        float o = bc[tid];
        #pragma unroll
        for (int j = 0; j < 12; ++j) o += hg[j] * Wc[j*10 + tid];
        out[g*10 + tid] = o;
    }
}

extern "C" void kernel_launch(void* const* d_in, const int* in_sizes, int n_in,
                              void* d_out, int out_size, void* d_ws, size_t ws_size,
                              hipStream_t stream) {
    const float* h   = (const float*)d_in[0];
    const int* src   = (const int*)d_in[1];
    const int* dst   = (const int*)d_in[2];
    const int* gid   = (const int*)d_in[3];
    const float* W1a = (const float*)d_in[4];
    const float* b1a = (const float*)d_in[5];
    const float* W1b = (const float*)d_in[6];
    const float* b1b = (const float*)d_in[7];
    const float* W2a = (const float*)d_in[8];
    const float* b2a = (const float*)d_in[9];
    const float* W2b = (const float*)d_in[10];
    const float* b2b = (const float*)d_in[11];
    const float* Wc  = (const float*)d_in[12];
    const float* bc  = (const float*)d_in[13];
    float* out = (float*)d_out;

    float* ws = (float*)d_ws;
    float* W1eff = ws;                    // 3072
    float* b1eff = ws + 3072;             // 12
    float* W2eff = ws + 3084;             // 288
    float* b2eff = ws + 3372;             // 12 -> 3384
    float* p1t   = ws + 3384;             // 600000
    float* p1b   = ws + 603384;           // 600000
    float* p2t   = ws + 1203384;          // 600000
    float* p2b   = ws + 1803384;          // 600000
    float* acc1  = ws + 2403384;          // 600000
    float* acc2  = ws + 3003384;          // 600000 -> 3603384
    // pairs (6.4 MB) aliased over p2t/p2b/acc1 — dead during CSR build,
    // B2 completes before gather/finalize write them.
    unsigned long long* pairs = (unsigned long long*)(ws + 1203384);   // 800000 x 8B
    // ---- zeroed region (deg, bcursor contiguous) ----
    int*   deg        = (int*)(ws + 3603384);   // 50000
    int*   bcursor    = (int*)(ws + 3653384);   // 196
    // ---- end zeroed region ----
    int*   row_start  = (int*)(ws + 3653580);   // 50001
    int*   bsums      = (int*)(ws + 3703581);   // 196
    int*   boffs      = (int*)(ws + 3703777);   // 196
    int*   gstart     = (int*)(ws + 3703973);   // 513
    int*   sorted_src = (int*)(ws + 3704486);   // 800000 -> 4504486 floats (~18 MB)

    hipMemsetAsync(deg, 0, (size_t)(50000 + 196) * sizeof(int), stream);

    fold_kernel<<<14, 256, 0, stream>>>(W1a, b1a, W1b, b1b, W2a, b2a, W2b, b2b,
                                        W1eff, b1eff, W2eff, b2eff);

    deg_kernel<<<(NE + 255) / 256, 256, 0, stream>>>(dst, deg);
    bsum_kernel<<<SCAN_BLOCKS, 256, 0, stream>>>(deg, bsums);
    bscan_kernel<<<1, 256, 0, stream>>>(bsums, boffs);
    rowscan_kernel<<<SCAN_BLOCKS, 256, 0, stream>>>(deg, boffs, row_start);

    bucket_scatter_kernel<<<B1_BLOCKS, 256, 0, stream>>>(src, dst, row_start, bcursor, pairs);
    fine_place_kernel<<<NB, 256, 0, stream>>>(pairs, row_start, sorted_src);

    gstart_kernel<<<(NN + 255) / 256, 256, 0, stream>>>(gid, gstart);

    p1_kernel<<<(NN + 255) / 256, 256, 0, stream>>>(h, W1eff, p1t, p1b);

    gather_kernel<<<(NN * 12 + 255) / 256, 256, 0, stream>>>(row_start, sorted_src, p1b, acc1);
    finalize1_kernel<<<(NN + 255) / 256, 256, 0, stream>>>(p1t, acc1, deg, b1eff, W2eff, p2t, p2b);

    gather_kernel<<<(NN * 12 + 255) / 256, 256, 0, stream>>>(row_start, sorted_src, p2b, acc2);

    graph_kernel<<<NG, 256, 0, stream>>>(p2t, acc2, deg, gstart, b2eff, Wc, bc, out);
}

// Round 7
// 159.175 us; speedup vs baseline: 2.2745x; 1.1304x over previous
//
#include <hip/hip_runtime.h>
#include <hip/hip_bf16.h>

#define NN 50000
#define NE 800000
#define NG 512
#define IND 128
#define MIDD 12
#define SCAN_BLOCKS 196   // 196*256 = 50176 >= NN+1
#define NB 196            // coarse buckets: dst>>8, 256 nodes each
#define B1_CHUNK 2048
#define B1_BLOCKS ((NE + B1_CHUNK - 1) / B1_CHUNK)   // 391

// ---------------- zero deg (replaces slow rocclr fillBuffer) -------------------
__global__ void zero_kernel(int* __restrict__ deg) {
    int i = blockIdx.x * blockDim.x + threadIdx.x;
    if (i < NN) deg[i] = 0;
}

// ---------------- fold weights: W1eff=[256,12], b1eff, W2eff=[24,12], b2eff ----
__global__ void fold_kernel(const float* __restrict__ W1a, const float* __restrict__ b1a,
                            const float* __restrict__ W1b, const float* __restrict__ b1b,
                            const float* __restrict__ W2a, const float* __restrict__ b2a,
                            const float* __restrict__ W2b, const float* __restrict__ b2b,
                            float* __restrict__ W1eff, float* __restrict__ b1eff,
                            float* __restrict__ W2eff, float* __restrict__ b2eff) {
    int t = blockIdx.x * blockDim.x + threadIdx.x;
    if (t < 3072) {
        int r = t / 12, c = t % 12;
        float acc = 0.f;
        for (int k = 0; k < 256; ++k) acc += W1a[r*256 + k] * W1b[k*12 + c];
        W1eff[r*12 + c] = acc;
    } else if (t < 3084) {
        int c = t - 3072;
        float acc = b1b[c];
        for (int k = 0; k < 256; ++k) acc += b1a[k] * W1b[k*12 + c];
        b1eff[c] = acc;
    } else if (t < 3372) {
        int u = t - 3084;
        int r = u / 12, c = u % 12;
        float acc = 0.f;
        for (int k = 0; k < 256; ++k) acc += W2a[r*256 + k] * W2b[k*12 + c];
        W2eff[r*12 + c] = acc;
    } else if (t < 3384) {
        int c = t - 3372;
        float acc = b2b[c];
        for (int k = 0; k < 256; ++k) acc += b2a[k] * W2b[k*12 + c];
        b2eff[c] = acc;
    }
}

// ---------------- p1: h [NN,128] @ W1eff -> p1_top [NN,12], p1_bot [NN,12] -----
__global__ void p1_kernel(const float* __restrict__ h, const float* __restrict__ W1eff,
                          float* __restrict__ p1t, float* __restrict__ p1b) {
    int n = blockIdx.x * blockDim.x + threadIdx.x;
    if (n >= NN) return;
    const float4* hrow = (const float4*)(h + (size_t)n * 128);
    float acc[24];
    #pragma unroll
    for (int j = 0; j < 24; ++j) acc[j] = 0.f;
    #pragma unroll 4
    for (int kq = 0; kq < 32; ++kq) {
        float4 hv = hrow[kq];
        #pragma unroll
        for (int u = 0; u < 4; ++u) {
            int k = kq * 4 + u;
            float hx = u == 0 ? hv.x : (u == 1 ? hv.y : (u == 2 ? hv.z : hv.w));
            const float4* wt = (const float4*)(W1eff + k * 12);
            const float4* wb = (const float4*)(W1eff + (128 + k) * 12);
            #pragma unroll
            for (int q = 0; q < 3; ++q) {
                float4 a = wt[q];
                float4 b = wb[q];
                acc[q*4 + 0]      += hx * a.x;
                acc[q*4 + 1]      += hx * a.y;
                acc[q*4 + 2]      += hx * a.z;
                acc[q*4 + 3]      += hx * a.w;
                acc[12 + q*4 + 0] += hx * b.x;
                acc[12 + q*4 + 1] += hx * b.y;
                acc[12 + q*4 + 2] += hx * b.z;
                acc[12 + q*4 + 3] += hx * b.w;
            }
        }
    }
    float* pt = p1t + (size_t)n * 12;
    float* pb = p1b + (size_t)n * 12;
    #pragma unroll
    for (int c = 0; c < 12; ++c) pt[c] = acc[c];
    #pragma unroll
    for (int c = 0; c < 12; ++c) pb[c] = acc[12 + c];
}

// ---------------- CSR build: deg histogram -------------------------------------
__global__ void deg_kernel(const int* __restrict__ dst, int* __restrict__ deg) {
    int e = blockIdx.x * blockDim.x + threadIdx.x;
    if (e >= NE) return;
    atomicAdd(&deg[dst[e]], 1);
}

// ---------------- parallel scan stage 1: per-block sums ------------------------
__global__ void bsum_kernel(const int* __restrict__ deg, int* __restrict__ bsums) {
    __shared__ int sh[256];
    int tid = threadIdx.x;
    int i = blockIdx.x * 256 + tid;
    sh[tid] = (i < NN) ? deg[i] : 0;
    __syncthreads();
    for (int off = 128; off > 0; off >>= 1) {
        if (tid < off) sh[tid] += sh[tid + off];
        __syncthreads();
    }
    if (tid == 0) bsums[blockIdx.x] = sh[0];
}

// ---------------- parallel scan stage 2: scan block sums (1 block) -------------
__global__ void bscan_kernel(const int* __restrict__ bsums, int* __restrict__ boffs) {
    __shared__ int sh[256];
    int tid = threadIdx.x;
    int v = (tid < SCAN_BLOCKS) ? bsums[tid] : 0;
    sh[tid] = v;
    __syncthreads();
    for (int off = 1; off < 256; off <<= 1) {
        int t = (tid >= off) ? sh[tid - off] : 0;
        __syncthreads();
        sh[tid] += t;
        __syncthreads();
    }
    if (tid < SCAN_BLOCKS) boffs[tid] = sh[tid] - v;  // exclusive
}

// ---------------- parallel scan stage 3: per-block exclusive scan + write ------
__global__ void rowscan_kernel(const int* __restrict__ deg, const int* __restrict__ boffs,
                               int* __restrict__ row_start) {
    __shared__ int sh[256];
    int tid = threadIdx.x;
    int i = blockIdx.x * 256 + tid;
    int v = (i < NN) ? deg[i] : 0;
    sh[tid] = v;
    __syncthreads();
    for (int off = 1; off < 256; off <<= 1) {
        int t = (tid >= off) ? sh[tid - off] : 0;
        __syncthreads();
        sh[tid] += t;
        __syncthreads();
    }
    if (i <= NN) row_start[i] = boffs[blockIdx.x] + sh[tid] - v;
}

// ---------------- B1a: per-block coarse-bucket histogram -----------------------
__global__ void hist_kernel(const int* __restrict__ dst, int* __restrict__ hist_mat) {
    __shared__ int hist[NB];
    int tid = threadIdx.x;
    for (int i = tid; i < NB; i += 256) hist[i] = 0;
    __syncthreads();
    int e0 = blockIdx.x * B1_CHUNK;
    #pragma unroll
    for (int k = 0; k < 8; ++k) {
        int e = e0 + tid + k * 256;
        if (e < NE) atomicAdd(&hist[dst[e] >> 8], 1);
    }
    __syncthreads();
    int* row = hist_mat + blockIdx.x * NB;
    for (int i = tid; i < NB; i += 256) row[i] = hist[i];
}

// ---------------- B1b: per-bucket exclusive scan over blocks -------------------
__global__ void offs_kernel(const int* __restrict__ hist_mat, const int* __restrict__ row_start,
                            int* __restrict__ off_mat) {
    __shared__ int sh[512];
    int tid = threadIdx.x;    // 512 threads
    int b = blockIdx.x;
    int v = (tid < B1_BLOCKS) ? hist_mat[tid * NB + b] : 0;
    sh[tid] = v;
    __syncthreads();
    for (int off = 1; off < 512; off <<= 1) {
        int t = (tid >= off) ? sh[tid - off] : 0;
        __syncthreads();
        sh[tid] += t;
        __syncthreads();
    }
    if (tid < B1_BLOCKS) off_mat[tid * NB + b] = row_start[b << 8] + sh[tid] - v;
}

// ---------------- B1c: place (src,dst) pairs into coarse regions, no g-atomics -
__global__ void place_pairs_kernel(const int* __restrict__ src, const int* __restrict__ dst,
                                   const int* __restrict__ off_mat,
                                   unsigned long long* __restrict__ pairs) {
    __shared__ int lbase[NB];
    __shared__ int lcur[NB];
    int tid = threadIdx.x;
    const int* orow = off_mat + blockIdx.x * NB;
    for (int i = tid; i < NB; i += 256) {
        lbase[i] = orow[i];
        lcur[i] = 0;
    }
    __syncthreads();
    int e0 = blockIdx.x * B1_CHUNK;
    #pragma unroll
    for (int k = 0; k < 8; ++k) {
        int e = e0 + tid + k * 256;
        if (e < NE) {
            int dd = dst[e];
            int ss = src[e];
            int bb = dd >> 8;
            int idx = atomicAdd(&lcur[bb], 1);
            pairs[lbase[bb] + idx] = ((unsigned long long)(unsigned)ss << 32) | (unsigned)dd;
        }
    }
}

// ---------------- B2: place pairs within bucket -> sorted_src ------------------
__global__ void fine_place_kernel(const unsigned long long* __restrict__ pairs,
                                  const int* __restrict__ row_start,
                                  int* __restrict__ sorted_src) {
    __shared__ int rs[257];
    __shared__ int cnt[256];
    int tid = threadIdx.x;
    int b = blockIdx.x;
    int n0 = b << 8;
    int n1 = min(n0 + 256, NN);
    int nloc = n1 - n0;
    for (int i = tid; i <= nloc; i += 256) rs[i] = row_start[n0 + i];
    cnt[tid] = 0;
    __syncthreads();
    int R0 = rs[0], R1 = rs[nloc];
    for (int i = R0 + tid; i < R1; i += 256) {
        unsigned long long pr = pairs[i];
        int dd = (int)(pr & 0xffffffffULL);
        int ss = (int)(pr >> 32);
        int ln = dd - n0;
        int off = atomicAdd(&cnt[ln], 1);
        sorted_src[rs[ln] + off] = ss;
    }
}

// ---------------- gather: acc[n,c] = sum over in-edges of p[src,c] -------------
__global__ void gather_kernel(const int* __restrict__ row_start, const int* __restrict__ sorted_src,
                              const float* __restrict__ p, float* __restrict__ acc) {
    int t = blockIdx.x * blockDim.x + threadIdx.x;
    if (t >= NN * 12) return;
    int n = t / 12, c = t - n * 12;
    int r0 = row_start[n], r1 = row_start[n + 1];
    float s = 0.f;
    if (r0 < r1) {
        int sn = sorted_src[r0];                 // software-pipelined prefetch
        for (int i = r0 + 1; i < r1; ++i) {
            int sn_next = sorted_src[i];
            s += p[sn * 12 + c];
            sn = sn_next;
        }
        s += p[sn * 12 + c];
    }
    acc[t] = s;
}

// ---------------- finalize layer1 + compute p2_top/p2_bot ----------------------
__global__ void finalize1_kernel(const float* __restrict__ p1t, const float* __restrict__ acc1,
                                 const int* __restrict__ deg, const float* __restrict__ b1eff,
                                 const float* __restrict__ W2eff,
                                 float* __restrict__ p2t, float* __restrict__ p2b) {
    __shared__ float w2[288];
    __shared__ float b1[12];
    int tid = threadIdx.x;
    for (int i = tid; i < 288; i += 256) w2[i] = W2eff[i];
    if (tid < 12) b1[tid] = b1eff[tid];
    __syncthreads();
    int n = blockIdx.x * blockDim.x + tid;
    if (n >= NN) return;
    int dg = deg[n];
    float inv = dg > 0 ? 1.f / (float)dg : 0.f;
    float h1[12];
    #pragma unroll
    for (int j = 0; j < 12; ++j) {
        float v = p1t[n*12 + j] + acc1[n*12 + j] * inv + b1[j];
        h1[j] = v > 0.f ? v : 0.f;
    }
    #pragma unroll
    for (int co = 0; co < 12; ++co) {
        float a = 0.f, b = 0.f;
        #pragma unroll
        for (int k = 0; k < 12; ++k) {
            a += h1[k] * w2[k*12 + co];
            b += h1[k] * w2[(12+k)*12 + co];
        }
        p2t[n*12 + co] = a;
        p2b[n*12 + co] = b;
    }
}

// ---------------- graph boundaries from sorted graph_id ------------------------
__global__ void gstart_kernel(const int* __restrict__ gid, int* __restrict__ gstart) {
    int n = blockIdx.x * blockDim.x + threadIdx.x;
    if (n >= NN) return;
    int cur = gid[n];
    int prev = (n == 0) ? -1 : gid[n - 1];
    for (int g = prev + 1; g <= cur; ++g) gstart[g] = n;
    if (n == NN - 1) {
        for (int g = cur + 1; g <= NG; ++g) gstart[g] = NN;
    }
}

// ---------------- per-graph: finalize2 + segment mean + @Wc + bc ---------------
__global__ void graph_kernel(const float* __restrict__ p2t, const float* __restrict__ acc2,
                             const int* __restrict__ deg, const int* __restrict__ gstart,
                             const float* __restrict__ b2eff, const float* __restrict__ Wc,
                             const float* __restrict__ bc, float* __restrict__ out) {
    __shared__ float sh[252];
    __shared__ float hg[12];
    int g = blockIdx.x;
    int r0 = gstart[g], r1 = gstart[g + 1];
    int tid = threadIdx.x;
    int group = tid / 12, ch = tid - group * 12;
    if (tid < 252) {
        float b2 = b2eff[ch];
        float s = 0.f;
        for (int n = r0 + group; n < r1; n += 21) {
            int dg = deg[n];
            float inv = dg > 0 ? 1.f / (float)dg : 0.f;
            float v = p2t[n*12 + ch] + acc2[n*12 + ch] * inv + b2;
            s += v > 0.f ? v : 0.f;
        }
        sh[tid] = s;
    }
    __syncthreads();
    if (tid < 12) {
        float tot = 0.f;
        #pragma unroll
        for (int k = 0; k < 21; ++k) tot += sh[k*12 + tid];
        int cntn = r1 - r0;
        hg[tid] = cntn > 0 ? tot / (float)cntn : 0.f;
    }
    __syncthreads();
    if (tid < 10) {
        float o = bc[tid];
        #pragma unroll
        for (int j = 0; j < 12; ++j) o += hg[j] * Wc[j*10 + tid];
        out[g*10 + tid] = o;
    }
}

extern "C" void kernel_launch(void* const* d_in, const int* in_sizes, int n_in,
                              void* d_out, int out_size, void* d_ws, size_t ws_size,
                              hipStream_t stream) {
    const float* h   = (const float*)d_in[0];
    const int* src   = (const int*)d_in[1];
    const int* dst   = (const int*)d_in[2];
    const int* gid   = (const int*)d_in[3];
    const float* W1a = (const float*)d_in[4];
    const float* b1a = (const float*)d_in[5];
    const float* W1b = (const float*)d_in[6];
    const float* b1b = (const float*)d_in[7];
    const float* W2a = (const float*)d_in[8];
    const float* b2a = (const float*)d_in[9];
    const float* W2b = (const float*)d_in[10];
    const float* b2b = (const float*)d_in[11];
    const float* Wc  = (const float*)d_in[12];
    const float* bc  = (const float*)d_in[13];
    float* out = (float*)d_out;

    float* ws = (float*)d_ws;
    float* W1eff = ws;                    // 3072
    float* b1eff = ws + 3072;             // 12
    float* W2eff = ws + 3084;             // 288
    float* b2eff = ws + 3372;             // 12 -> 3384
    float* p1t   = ws + 3384;             // 600000
    float* p1b   = ws + 603384;           // 600000
    float* p2t   = ws + 1203384;          // 600000
    float* p2b   = ws + 1803384;          // 600000
    float* acc1  = ws + 2403384;          // 600000
    float* acc2  = ws + 3003384;          // 600000 -> 3603384
    // pairs (6.4 MB) aliased over p2t/p2b/acc1-head — dead during CSR build;
    // fine_place completes before gather/finalize1 write them.
    unsigned long long* pairs = (unsigned long long*)(ws + 1203384);   // 800000 x 8B
    // hist_mat/off_mat (76,636 ints each) alias the p1t/p1b region — dead until
    // p1_kernel runs, which is after fine_place.
    int*   hist_mat   = (int*)(ws + 3384);      // 391*196 = 76636
    int*   off_mat    = (int*)(ws + 80020);     // 76636 -> 156656 (< 603384)
    int*   deg        = (int*)(ws + 3603384);   // 50000
    int*   row_start  = (int*)(ws + 3653384);   // 50001
    int*   bsums      = (int*)(ws + 3703385);   // 196
    int*   boffs      = (int*)(ws + 3703581);   // 196
    int*   gstart     = (int*)(ws + 3703777);   // 513
    int*   sorted_src = (int*)(ws + 3704290);   // 800000 -> 4504290 floats (~18 MB)

    zero_kernel<<<SCAN_BLOCKS, 256, 0, stream>>>(deg);

    fold_kernel<<<14, 256, 0, stream>>>(W1a, b1a, W1b, b1b, W2a, b2a, W2b, b2b,
                                        W1eff, b1eff, W2eff, b2eff);

    deg_kernel<<<(NE + 255) / 256, 256, 0, stream>>>(dst, deg);
    bsum_kernel<<<SCAN_BLOCKS, 256, 0, stream>>>(deg, bsums);
    bscan_kernel<<<1, 256, 0, stream>>>(bsums, boffs);
    rowscan_kernel<<<SCAN_BLOCKS, 256, 0, stream>>>(deg, boffs, row_start);

    hist_kernel<<<B1_BLOCKS, 256, 0, stream>>>(dst, hist_mat);
    offs_kernel<<<NB, 512, 0, stream>>>(hist_mat, row_start, off_mat);
    place_pairs_kernel<<<B1_BLOCKS, 256, 0, stream>>>(src, dst, off_mat, pairs);
    fine_place_kernel<<<NB, 256, 0, stream>>>(pairs, row_start, sorted_src);

    gstart_kernel<<<(NN + 255) / 256, 256, 0, stream>>>(gid, gstart);

    p1_kernel<<<(NN + 255) / 256, 256, 0, stream>>>(h, W1eff, p1t, p1b);

    gather_kernel<<<(NN * 12 + 255) / 256, 256, 0, stream>>>(row_start, sorted_src, p1b, acc1);
    finalize1_kernel<<<(NN + 255) / 256, 256, 0, stream>>>(p1t, acc1, deg, b1eff, W2eff, p2t, p2b);

    gather_kernel<<<(NN * 12 + 255) / 256, 256, 0, stream>>>(row_start, sorted_src, p2b, acc2);

    graph_kernel<<<NG, 256, 0, stream>>>(p2t, acc2, deg, gstart, b2eff, Wc, bc, out);
}

// Round 8
// 117.412 us; speedup vs baseline: 3.0835x; 1.3557x over previous
//
#include <hip/hip_runtime.h>
#include <hip/hip_bf16.h>

#define NN 50000
#define NE 800000
#define NG 512
#define IND 128
#define MIDD 12
#define NB 196            // coarse buckets: dst>>8, 256 nodes each
#define B1_CHUNK 2048
#define B1_BLOCKS ((NE + B1_CHUNK - 1) / B1_CHUNK)   // 391
#define NPB 85            // nodes per block in fused gather1

typedef unsigned long long ull;

// ---------------- fold weights: W1eff=[256,12], b1eff, W2eff=[24,12], b2eff ----
__global__ void fold_kernel(const float* __restrict__ W1a, const float* __restrict__ b1a,
                            const float* __restrict__ W1b, const float* __restrict__ b1b,
                            const float* __restrict__ W2a, const float* __restrict__ b2a,
                            const float* __restrict__ W2b, const float* __restrict__ b2b,
                            float* __restrict__ W1eff, float* __restrict__ b1eff,
                            float* __restrict__ W2eff, float* __restrict__ b2eff) {
    int t = blockIdx.x * blockDim.x + threadIdx.x;
    if (t < 3072) {
        int r = t / 12, c = t % 12;
        float acc = 0.f;
        for (int k = 0; k < 256; ++k) acc += W1a[r*256 + k] * W1b[k*12 + c];
        W1eff[r*12 + c] = acc;
    } else if (t < 3084) {
        int c = t - 3072;
        float acc = b1b[c];
        for (int k = 0; k < 256; ++k) acc += b1a[k] * W1b[k*12 + c];
        b1eff[c] = acc;
    } else if (t < 3372) {
        int u = t - 3084;
        int r = u / 12, c = u % 12;
        float acc = 0.f;
        for (int k = 0; k < 256; ++k) acc += W2a[r*256 + k] * W2b[k*12 + c];
        W2eff[r*12 + c] = acc;
    } else if (t < 3384) {
        int c = t - 3372;
        float acc = b2b[c];
        for (int k = 0; k < 256; ++k) acc += b2a[k] * W2b[k*12 + c];
        b2eff[c] = acc;
    }
}

// ---------------- p1: h [NN,128] @ W1eff -> p1_top [NN,12], p1_bot [NN,12] -----
__global__ void p1_kernel(const float* __restrict__ h, const float* __restrict__ W1eff,
                          float* __restrict__ p1t, float* __restrict__ p1b) {
    int n = blockIdx.x * blockDim.x + threadIdx.x;
    if (n >= NN) return;
    const float4* hrow = (const float4*)(h + (size_t)n * 128);
    float acc[24];
    #pragma unroll
    for (int j = 0; j < 24; ++j) acc[j] = 0.f;
    #pragma unroll 4
    for (int kq = 0; kq < 32; ++kq) {
        float4 hv = hrow[kq];
        #pragma unroll
        for (int u = 0; u < 4; ++u) {
            int k = kq * 4 + u;
            float hx = u == 0 ? hv.x : (u == 1 ? hv.y : (u == 2 ? hv.z : hv.w));
            const float4* wt = (const float4*)(W1eff + k * 12);
            const float4* wb = (const float4*)(W1eff + (128 + k) * 12);
            #pragma unroll
            for (int q = 0; q < 3; ++q) {
                float4 a = wt[q];
                float4 b = wb[q];
                acc[q*4 + 0]      += hx * a.x;
                acc[q*4 + 1]      += hx * a.y;
                acc[q*4 + 2]      += hx * a.z;
                acc[q*4 + 3]      += hx * a.w;
                acc[12 + q*4 + 0] += hx * b.x;
                acc[12 + q*4 + 1] += hx * b.y;
                acc[12 + q*4 + 2] += hx * b.z;
                acc[12 + q*4 + 3] += hx * b.w;
            }
        }
    }
    float* pt = p1t + (size_t)n * 12;
    float* pb = p1b + (size_t)n * 12;
    #pragma unroll
    for (int c = 0; c < 12; ++c) pt[c] = acc[c];
    #pragma unroll
    for (int c = 0; c < 12; ++c) pb[c] = acc[12 + c];
}

// ---------------- B1a: per-block coarse-bucket histogram -----------------------
__global__ void hist_kernel(const int* __restrict__ dst, int* __restrict__ hist_mat) {
    __shared__ int hist[NB];
    int tid = threadIdx.x;
    for (int i = tid; i < NB; i += 256) hist[i] = 0;
    __syncthreads();
    int e0 = blockIdx.x * B1_CHUNK;
    #pragma unroll
    for (int k = 0; k < 8; ++k) {
        int e = e0 + tid + k * 256;
        if (e < NE) atomicAdd(&hist[dst[e] >> 8], 1);
    }
    __syncthreads();
    int* row = hist_mat + blockIdx.x * NB;
    for (int i = tid; i < NB; i += 256) row[i] = hist[i];
}

// ---------------- B1b: per-bucket local scan over blocks + bucket totals -------
__global__ void offs_kernel(const int* __restrict__ hist_mat,
                            int* __restrict__ off_mat, int* __restrict__ btot) {
    __shared__ int sh[512];
    int tid = threadIdx.x;    // 512 threads
    int b = blockIdx.x;
    int v = (tid < B1_BLOCKS) ? hist_mat[tid * NB + b] : 0;
    sh[tid] = v;
    __syncthreads();
    for (int off = 1; off < 512; off <<= 1) {
        int t = (tid >= off) ? sh[tid - off] : 0;
        __syncthreads();
        sh[tid] += t;
        __syncthreads();
    }
    if (tid < B1_BLOCKS) off_mat[tid * NB + b] = sh[tid] - v;   // local exclusive
    if (tid == B1_BLOCKS - 1) btot[b] = sh[tid];                // bucket total
}

// ---------------- B1b': exclusive scan of bucket totals -> bucket_base ---------
__global__ void bucket_scan_kernel(const int* __restrict__ btot, int* __restrict__ bucket_base) {
    __shared__ int sh[256];
    int tid = threadIdx.x;
    int v = (tid < NB) ? btot[tid] : 0;
    sh[tid] = v;
    __syncthreads();
    for (int off = 1; off < 256; off <<= 1) {
        int t = (tid >= off) ? sh[tid - off] : 0;
        __syncthreads();
        sh[tid] += t;
        __syncthreads();
    }
    if (tid < NB) bucket_base[tid] = sh[tid] - v;
    if (tid == NB - 1) bucket_base[NB] = sh[tid];   // == NE
}

// ---------------- B1c: place (src,dst) pairs into coarse regions ---------------
__global__ void place_pairs_kernel(const int* __restrict__ src, const int* __restrict__ dst,
                                   const int* __restrict__ off_mat, const int* __restrict__ bucket_base,
                                   ull* __restrict__ pairs) {
    __shared__ int lbase[NB];
    __shared__ int lcur[NB];
    int tid = threadIdx.x;
    const int* orow = off_mat + blockIdx.x * NB;
    for (int i = tid; i < NB; i += 256) {
        lbase[i] = bucket_base[i] + orow[i];
        lcur[i] = 0;
    }
    __syncthreads();
    int e0 = blockIdx.x * B1_CHUNK;
    #pragma unroll
    for (int k = 0; k < 8; ++k) {
        int e = e0 + tid + k * 256;
        if (e < NE) {
            int dd = dst[e];
            int ss = src[e];
            int bb = dd >> 8;
            int idx = atomicAdd(&lcur[bb], 1);
            pairs[lbase[bb] + idx] = ((ull)(unsigned)ss << 32) | (unsigned)dd;
        }
    }
}

// ---------------- B2: per-bucket node histogram + scan -> row_start + place ----
__global__ void fine_place_kernel(const ull* __restrict__ pairs,
                                  const int* __restrict__ bucket_base,
                                  int* __restrict__ row_start,
                                  int* __restrict__ sorted_src) {
    __shared__ int cnt[256];
    __shared__ int sc[256];
    __shared__ int rs[257];
    int tid = threadIdx.x;
    int b = blockIdx.x;
    int n0 = b << 8;
    int nloc = min(256, NN - n0);
    int R0 = bucket_base[b], R1 = bucket_base[b + 1];
    cnt[tid] = 0;
    __syncthreads();
    // pass 1: node-level histogram of this bucket's pairs
    for (int i = R0 + tid; i < R1; i += 256) {
        atomicAdd(&cnt[(int)(pairs[i] & 255ULL)], 1);
    }
    __syncthreads();
    // exclusive scan -> local row starts
    int v = cnt[tid];
    sc[tid] = v;
    __syncthreads();
    for (int off = 1; off < 256; off <<= 1) {
        int t = (tid >= off) ? sc[tid - off] : 0;
        __syncthreads();
        sc[tid] += t;
        __syncthreads();
    }
    rs[tid] = R0 + sc[tid] - v;
    if (tid == 255) rs[256] = R0 + sc[255];
    cnt[tid] = 0;   // reset for placement cursors
    __syncthreads();
    // write row_start (next bucket writes our n0+256 as its R0; values agree)
    if (tid < nloc) row_start[n0 + tid] = rs[tid];
    if (b == NB - 1 && tid == 0) row_start[NN] = R1;
    // pass 2: place (pairs are L2-hot from pass 1)
    for (int i = R0 + tid; i < R1; i += 256) {
        ull pr = pairs[i];
        int dd = (int)(pr & 0xffffffffULL);
        int ss = (int)(pr >> 32);
        int ln = dd & 255;
        int off = atomicAdd(&cnt[ln], 1);
        sorted_src[rs[ln] + off] = ss;
    }
}

// ---------------- fused gather1 + finalize1 ------------------------------------
// 3 threads per node (4 channels each, float4 loads); LDS handoff to per-node
// finalize: h1 = relu(p1t + acc/deg + b1); (p2t,p2b) = h1 @ W2eff halves.
__global__ void gather_fin1_kernel(const int* __restrict__ row_start, const int* __restrict__ sorted_src,
                                   const float* __restrict__ p1t, const float* __restrict__ p1b,
                                   const float* __restrict__ b1eff, const float* __restrict__ W2eff,
                                   float* __restrict__ p2t, float* __restrict__ p2b) {
    __shared__ float hacc[NPB * 13];   // stride 13: conflict-free (13 coprime 32)
    __shared__ float hinv[NPB];
    __shared__ float w2[288];
    __shared__ float b1[12];
    int tid = threadIdx.x;
    for (int i = tid; i < 288; i += 256) w2[i] = W2eff[i];
    if (tid < 12) b1[tid] = b1eff[tid];
    int li = tid / 3, q = tid - li * 3;
    int n0 = blockIdx.x * NPB;
    if (li < NPB) {
        int n = n0 + li;
        if (n < NN) {
            int r0 = row_start[n], r1 = row_start[n + 1];
            float4 s = make_float4(0.f, 0.f, 0.f, 0.f);
            for (int i = r0; i < r1; ++i) {
                int sn = sorted_src[i];
                float4 v = ((const float4*)(p1b + (size_t)sn * 12))[q];
                s.x += v.x; s.y += v.y; s.z += v.z; s.w += v.w;
            }
            float* hp = &hacc[li * 13 + q * 4];
            hp[0] = s.x; hp[1] = s.y; hp[2] = s.z; hp[3] = s.w;
            if (q == 0) hinv[li] = (r1 > r0) ? 1.f / (float)(r1 - r0) : 0.f;
        }
    }
    __syncthreads();
    int n = n0 + tid;
    if (tid < NPB && n < NN) {
        float inv = hinv[tid];
        const float4* ptr = (const float4*)(p1t + (size_t)n * 12);
        float4 a0 = ptr[0], a1 = ptr[1], a2 = ptr[2];
        float pt[12] = {a0.x,a0.y,a0.z,a0.w, a1.x,a1.y,a1.z,a1.w, a2.x,a2.y,a2.z,a2.w};
        float h1[12];
        #pragma unroll
        for (int j = 0; j < 12; ++j) {
            float v = pt[j] + hacc[tid * 13 + j] * inv + b1[j];
            h1[j] = v > 0.f ? v : 0.f;
        }
        float oa[12], ob[12];
        #pragma unroll
        for (int co = 0; co < 12; ++co) {
            float A = 0.f, B = 0.f;
            #pragma unroll
            for (int k = 0; k < 12; ++k) {
                A += h1[k] * w2[k*12 + co];
                B += h1[k] * w2[(12+k)*12 + co];
            }
            oa[co] = A; ob[co] = B;
        }
        float4* ot = (float4*)(p2t + (size_t)n * 12);
        float4* ou = (float4*)(p2b + (size_t)n * 12);
        ot[0] = make_float4(oa[0],oa[1],oa[2],oa[3]);
        ot[1] = make_float4(oa[4],oa[5],oa[6],oa[7]);
        ot[2] = make_float4(oa[8],oa[9],oa[10],oa[11]);
        ou[0] = make_float4(ob[0],ob[1],ob[2],ob[3]);
        ou[1] = make_float4(ob[4],ob[5],ob[6],ob[7]);
        ou[2] = make_float4(ob[8],ob[9],ob[10],ob[11]);
    }
}

// ---------------- fused gather2 + finalize2 (elementwise per channel-quad) -----
__global__ void gather_fin2_kernel(const int* __restrict__ row_start, const int* __restrict__ sorted_src,
                                   const float* __restrict__ p2t, const float* __restrict__ p2b,
                                   const float* __restrict__ b2eff, float* __restrict__ h2) {
    int t = blockIdx.x * blockDim.x + threadIdx.x;
    if (t >= NN * 3) return;
    int n = t / 3, q = t - n * 3;
    int r0 = row_start[n], r1 = row_start[n + 1];
    float4 s = make_float4(0.f, 0.f, 0.f, 0.f);
    for (int i = r0; i < r1; ++i) {
        int sn = sorted_src[i];
        float4 v = ((const float4*)(p2b + (size_t)sn * 12))[q];
        s.x += v.x; s.y += v.y; s.z += v.z; s.w += v.w;
    }
    float inv = (r1 > r0) ? 1.f / (float)(r1 - r0) : 0.f;
    float4 pt = ((const float4*)(p2t + (size_t)n * 12))[q];
    const float* b2 = b2eff + q * 4;
    float4 o;
    o.x = pt.x + s.x * inv + b2[0]; o.x = o.x > 0.f ? o.x : 0.f;
    o.y = pt.y + s.y * inv + b2[1]; o.y = o.y > 0.f ? o.y : 0.f;
    o.z = pt.z + s.z * inv + b2[2]; o.z = o.z > 0.f ? o.z : 0.f;
    o.w = pt.w + s.w * inv + b2[3]; o.w = o.w > 0.f ? o.w : 0.f;
    ((float4*)(h2 + (size_t)n * 12))[q] = o;
}

// ---------------- graph boundaries from sorted graph_id ------------------------
__global__ void gstart_kernel(const int* __restrict__ gid, int* __restrict__ gstart) {
    int n = blockIdx.x * blockDim.x + threadIdx.x;
    if (n >= NN) return;
    int cur = gid[n];
    int prev = (n == 0) ? -1 : gid[n - 1];
    for (int g = prev + 1; g <= cur; ++g) gstart[g] = n;
    if (n == NN - 1) {
        for (int g = cur + 1; g <= NG; ++g) gstart[g] = NN;
    }
}

// ---------------- per-graph: segment mean of h2 + @Wc + bc ---------------------
__global__ void graph_kernel(const float* __restrict__ h2, const int* __restrict__ gstart,
                             const float* __restrict__ Wc, const float* __restrict__ bc,
                             float* __restrict__ out) {
    __shared__ float sh[252];
    __shared__ float hg[12];
    int g = blockIdx.x;
    int r0 = gstart[g], r1 = gstart[g + 1];
    int tid = threadIdx.x;
    int group = tid / 12, ch = tid - group * 12;
    if (tid < 252) {
        float s = 0.f;
        for (int n = r0 + group; n < r1; n += 21) s += h2[(size_t)n * 12 + ch];
        sh[tid] = s;
    }
    __syncthreads();
    if (tid < 12) {
        float tot = 0.f;
        #pragma unroll
        for (int k = 0; k < 21; ++k) tot += sh[k*12 + tid];
        int cntn = r1 - r0;
        hg[tid] = cntn > 0 ? tot / (float)cntn : 0.f;
    }
    __syncthreads();
    if (tid < 10) {
        float o = bc[tid];
        #pragma unroll
        for (int j = 0; j < 12; ++j) o += hg[j] * Wc[j*10 + tid];
        out[g*10 + tid] = o;
    }
}

extern "C" void kernel_launch(void* const* d_in, const int* in_sizes, int n_in,
                              void* d_out, int out_size, void* d_ws, size_t ws_size,
                              hipStream_t stream) {
    const float* h   = (const float*)d_in[0];
    const int* src   = (const int*)d_in[1];
    const int* dst   = (const int*)d_in[2];
    const int* gid   = (const int*)d_in[3];
    const float* W1a = (const float*)d_in[4];
    const float* b1a = (const float*)d_in[5];
    const float* W1b = (const float*)d_in[6];
    const float* b1b = (const float*)d_in[7];
    const float* W2a = (const float*)d_in[8];
    const float* b2a = (const float*)d_in[9];
    const float* W2b = (const float*)d_in[10];
    const float* b2b = (const float*)d_in[11];
    const float* Wc  = (const float*)d_in[12];
    const float* bc  = (const float*)d_in[13];
    float* out = (float*)d_out;

    float* ws = (float*)d_ws;
    float* W1eff = ws;                    // 3072
    float* b1eff = ws + 3072;             // 12
    float* W2eff = ws + 3084;             // 288
    float* b2eff = ws + 3372;             // 12 -> 3384
    float* p1t   = ws + 3384;             // 600000
    float* p1b   = ws + 603384;           // 600000
    float* p2t   = ws + 1203384;          // 600000
    float* p2b   = ws + 1803384;          // 600000
    float* h2    = ws + 2403384;          // 600000 -> 3003384
    // pairs (6.4 MB) alias p2t/p2b/h2-head — dead during CSR build; fine_place
    // completes before gather_fin1/gather_fin2 write them.
    ull*   pairs = (ull*)(ws + 1203384);        // 800000 x 8B -> ends at 2803384
    // hist_mat/off_mat alias p1t/p1b head — dead until p1_kernel (after CSR).
    int*   hist_mat    = (int*)(ws + 3384);     // 391*196 = 76636
    int*   off_mat     = (int*)(ws + 80020);    // 76636 -> 156656 (< 603384)
    int*   row_start   = (int*)(ws + 3003384);  // 50001
    int*   btot        = (int*)(ws + 3053385);  // 196
    int*   bucket_base = (int*)(ws + 3053581);  // 197
    int*   gstart      = (int*)(ws + 3053778);  // 513
    int*   sorted_src  = (int*)(ws + 3054291);  // 800000 -> 3854291 floats (~15.4 MB)

    fold_kernel<<<14, 256, 0, stream>>>(W1a, b1a, W1b, b1b, W2a, b2a, W2b, b2b,
                                        W1eff, b1eff, W2eff, b2eff);

    hist_kernel<<<B1_BLOCKS, 256, 0, stream>>>(dst, hist_mat);
    offs_kernel<<<NB, 512, 0, stream>>>(hist_mat, off_mat, btot);
    bucket_scan_kernel<<<1, 256, 0, stream>>>(btot, bucket_base);
    place_pairs_kernel<<<B1_BLOCKS, 256, 0, stream>>>(src, dst, off_mat, bucket_base, pairs);
    fine_place_kernel<<<NB, 256, 0, stream>>>(pairs, bucket_base, row_start, sorted_src);

    gstart_kernel<<<(NN + 255) / 256, 256, 0, stream>>>(gid, gstart);

    p1_kernel<<<(NN + 255) / 256, 256, 0, stream>>>(h, W1eff, p1t, p1b);

    gather_fin1_kernel<<<(NN + NPB - 1) / NPB, 256, 0, stream>>>(row_start, sorted_src,
                                                                 p1t, p1b, b1eff, W2eff, p2t, p2b);

    gather_fin2_kernel<<<(NN * 3 + 255) / 256, 256, 0, stream>>>(row_start, sorted_src,
                                                                 p2t, p2b, b2eff, h2);

    graph_kernel<<<NG, 256, 0, stream>>>(h2, gstart, Wc, bc, out);
}